// Round 6
// baseline (1788.914 us; speedup 1.0000x reference)
//
#include <hip/hip_runtime.h>
#include <math.h>

#define H 128

typedef __attribute__((ext_vector_type(8))) short short8;
typedef __attribute__((ext_vector_type(4))) float f32x4;

static const int SRC_T_[7] = {0, 0, 1, 1, 1, 2, 2};
static const int DST_T_[7] = {0, 1, 0, 1, 2, 1, 2};

__device__ __forceinline__ float eluf(float x) {
    return x > 0.f ? x : (__expf(x) - 1.f);
}
__device__ __forceinline__ unsigned short f2bf(float x) {  // RNE f32->bf16
    union { float f; unsigned int u; } v; v.f = x;
    unsigned int r = v.u + 0x7fffu + ((v.u >> 16) & 1u);
    return (unsigned short)(r >> 16);
}
__device__ __forceinline__ float bf2f(unsigned int u) {
    union { unsigned int u; float f; } v; v.u = u << 16;
    return v.f;
}

// ---------------------------------------------------------------------------
// hb[t] = bf16(elu(x @ W + b)); x:[n,64], W:[64,128]
__global__ __launch_bounds__(128) void k_input_linear(
    const float* __restrict__ x, const float* __restrict__ W,
    const float* __restrict__ b, unsigned short* __restrict__ hb, int n)
{
    __shared__ float Ws[64 * H];
    __shared__ float xs[16 * 64];
    __shared__ unsigned short os[16 * H];
    const int j = threadIdx.x;
    for (int i = j; i < 64 * H; i += 128) Ws[i] = W[i];
    const float bj = b[j];

    for (int r0 = blockIdx.x * 16; r0 < n; r0 += gridDim.x * 16) {
        const int nrows = min(16, n - r0);
        __syncthreads();
        for (int i = j; i < nrows * 64; i += 128) xs[i] = x[(size_t)r0 * 64 + i];
        __syncthreads();
        for (int i = 0; i < nrows; ++i) {
            float acc = bj;
#pragma unroll
            for (int k = 0; k < 64; k += 4) {
                float4 xv = *(const float4*)&xs[i * 64 + k];
                acc += xv.x * Ws[(k + 0) * H + j] + xv.y * Ws[(k + 1) * H + j]
                     + xv.z * Ws[(k + 2) * H + j] + xv.w * Ws[(k + 3) * H + j];
            }
            os[i * H + j] = f2bf(eluf(acc));
        }
        __syncthreads();
        uint2* d = (uint2*)&hb[(size_t)r0 * H];
        const uint2* s2 = (const uint2*)os;
        for (int i = j; i < nrows * 32; i += 128) d[i] = s2[i];
    }
}

// --------------------------- batched CSR build ------------------------------
struct CsrCtx {
    const int* src[7]; const int* dst[7]; const float* ea[7];
    int* csr_src[7]; uint2* csr_ea[7]; int* ptr[7];
    int* deg; int* cursor; int* bsum;
    int eOff[8];   // edge prefix
    int bOff[8];   // 256-block prefix per relation (deg/cursor padded to 256)
    int nd[7];
};

__global__ __launch_bounds__(256) void k_hist_all(CsrCtx C, int Etot)
{
    for (int e = blockIdx.x * 256 + threadIdx.x; e < Etot; e += gridDim.x * 256) {
        int r = 0;
        while (e >= C.eOff[r + 1]) ++r;
        const int le = e - C.eOff[r];
        atomicAdd(&C.deg[(C.bOff[r] << 8) + C.dst[r][le]], 1);
    }
}

__global__ __launch_bounds__(256) void k_scan_partial_all(CsrCtx C)
{
    __shared__ int s[256];
    const int b = blockIdx.x;
    int r = 0;
    while (b >= C.bOff[r + 1]) ++r;
    const int lb = b - C.bOff[r];
    const int tid = threadIdx.x;
    const int idx = lb * 256 + tid;
    s[tid] = idx < C.nd[r] ? C.deg[(C.bOff[r] << 8) + idx] : 0;
    __syncthreads();
    for (int off = 128; off > 0; off >>= 1) {
        if (tid < off) s[tid] += s[tid + off];
        __syncthreads();
    }
    if (tid == 0) C.bsum[b] = s[0];
}

__global__ __launch_bounds__(512) void k_scan_mid_all(CsrCtx C)
{
    __shared__ int s[512];
    const int r = blockIdx.x;
    const int nb = C.bOff[r + 1] - C.bOff[r];
    const int tid = threadIdx.x;
    const int v = tid < nb ? C.bsum[C.bOff[r] + tid] : 0;
    s[tid] = v;
    __syncthreads();
    for (int off = 1; off < 512; off <<= 1) {
        int t = (tid >= off) ? s[tid - off] : 0;
        __syncthreads();
        s[tid] += t;
        __syncthreads();
    }
    if (tid < nb) C.bsum[C.bOff[r] + tid] = s[tid] - v;  // exclusive
    if (tid == nb - 1) C.ptr[r][C.nd[r]] = s[tid];       // total
}

__global__ __launch_bounds__(256) void k_scan_final_all(CsrCtx C)
{
    __shared__ int s[256];
    const int b = blockIdx.x;
    int r = 0;
    while (b >= C.bOff[r + 1]) ++r;
    const int lb = b - C.bOff[r];
    const int tid = threadIdx.x;
    const int idx = lb * 256 + tid;
    const int v = idx < C.nd[r] ? C.deg[(C.bOff[r] << 8) + idx] : 0;
    s[tid] = v;
    __syncthreads();
    for (int off = 1; off < 256; off <<= 1) {
        int t = (tid >= off) ? s[tid - off] : 0;
        __syncthreads();
        s[tid] += t;
        __syncthreads();
    }
    if (idx < C.nd[r]) {
        const int excl = s[tid] - v + C.bsum[b];
        C.ptr[r][idx] = excl;
        C.cursor[(C.bOff[r] << 8) + idx] = excl;
    }
}

__global__ __launch_bounds__(256) void k_scatter_all(CsrCtx C, int Etot)
{
    for (int e = blockIdx.x * 256 + threadIdx.x; e < Etot; e += gridDim.x * 256) {
        int r = 0;
        while (e >= C.eOff[r + 1]) ++r;
        const int le = e - C.eOff[r];
        const int d = C.dst[r][le];
        const int pos = atomicAdd(&C.cursor[(C.bOff[r] << 8) + d], 1);
        C.csr_src[r][pos] = C.src[r][le];
        const float* eap = C.ea[r] + (size_t)3 * le;
        uint2 p;
        p.x = (unsigned int)f2bf(eap[0]) | ((unsigned int)f2bf(eap[1]) << 16);
        p.y = (unsigned int)f2bf(eap[2]);
        C.csr_ea[r][pos] = p;
    }
}

// ---------------------------------------------------------------------------
// Weight prep: W1,W2 [21][128k][128c] f32 -> wp [21][2][128c][128k] bf16
__global__ __launch_bounds__(256) void k_wprep(
    const float* __restrict__ W1, const float* __restrict__ W2,
    unsigned short* __restrict__ wp, int total)
{
    for (int i = blockIdx.x * 256 + threadIdx.x; i < total; i += gridDim.x * 256) {
        int lr = i >> 14, rem = i & 16383;
        int c = rem >> 7, k = rem & 127;
        wp[(size_t)(lr * 2 + 0) * 16384 + rem] = f2bf(W1[(size_t)lr * 16384 + k * H + c]);
        wp[(size_t)(lr * 2 + 1) * 16384 + rem] = f2bf(W2[(size_t)lr * 16384 + k * H + c]);
    }
}

// ---------------------------------------------------------------------------
// Batched gather-aggregate for one layer, all 7 relations:
//   z_r[d] = bf16( hb_dst[d] + sum_e relu(hb_src[csr_src] + ea@eW + eb) )
// 1 node per 64-lane group, 4 groups per block; relation via prefix lookup.
struct AggCtx {
    const int* ptr[7]; const int* csr_src[7]; const uint2* csr_ea[7];
    const unsigned short* hsrc[7]; const unsigned short* hdst[7];
    unsigned short* z[7];
    int nOff[8];
};

__global__ __launch_bounds__(256) void k_aggz_all(
    AggCtx A, const float* __restrict__ eW, const float* __restrict__ eb,
    int l, int ntot)
{
    const int g = blockIdx.x * 4 + (threadIdx.x >> 6);
    if (g >= ntot) return;
    int r = 0;
    while (g >= A.nOff[r + 1]) ++r;
    const int d = g - A.nOff[r];
    const int lane = threadIdx.x & 63;
    const int t2 = lane << 1;
    const int lr = l * 7 + r;
    const float* eWr = eW + (size_t)lr * 3 * H;
    const float* ebr = eb + (size_t)lr * H;
    const float w00 = eWr[t2],         w01 = eWr[t2 + 1];
    const float w10 = eWr[H + t2],     w11 = eWr[H + t2 + 1];
    const float w20 = eWr[2 * H + t2], w21 = eWr[2 * H + t2 + 1];
    const float b0 = ebr[t2], b1v = ebr[t2 + 1];

    const int p0 = A.ptr[r][d], p1 = A.ptr[r][d + 1];
    float acc0 = 0.f, acc1 = 0.f;
    const int* cs = A.csr_src[r];
    const uint2* ce = A.csr_ea[r];
    const unsigned short* hs = A.hsrc[r];
    for (int i = p0; i < p1; ++i) {
        const int s = cs[i];
        const uint2 ep = ce[i];
        const float a0 = bf2f(ep.x & 0xffffu);
        const float a1 = bf2f(ep.x >> 16);
        const float a2 = bf2f(ep.y & 0xffffu);
        const unsigned int hv = ((const unsigned int*)&hs[(size_t)s * H])[lane];
        acc0 += fmaxf(bf2f(hv & 0xffffu) + a0 * w00 + a1 * w10 + a2 * w20 + b0, 0.f);
        acc1 += fmaxf(bf2f(hv >> 16)     + a0 * w01 + a1 * w11 + a2 * w21 + b1v, 0.f);
    }
    const unsigned int hd = ((const unsigned int*)&A.hdst[r][(size_t)d * H])[lane];
    acc0 += bf2f(hd & 0xffffu);
    acc1 += bf2f(hd >> 16);
    ((unsigned int*)A.z[r])[d * 64 + lane] =
        (unsigned int)f2bf(acc0) | ((unsigned int)f2bf(acc1) << 16);
}

// ---------------------------------------------------------------------------
// Fused multi-relation MFMA MLP for one dst type, z precomputed in global:
//   hnew = elu( sum_rel (relu(z_rel@W1*bn+..)@W2 + b2) + hb )
// A-fragments read straight from z (global, L2-hot); only a1t (32 KB) in LDS.
template<int NREL>
__global__ __launch_bounds__(512, 6) void k_mlp_fused(
    const unsigned short* __restrict__ hb, unsigned short* __restrict__ hbw,
    float* __restrict__ fout,
    const unsigned short* __restrict__ wprep,
    const float* __restrict__ b1g, const float* __restrict__ g1g,
    const float* __restrict__ be1g, const float* __restrict__ b2g,
    const unsigned short* __restrict__ zA, const unsigned short* __restrict__ zB,
    const unsigned short* __restrict__ zC,
    int lrA, int lrB, int lrC, int n, int fin)
{
    __shared__ unsigned short a1t[128 * H];  // 32 KB, XOR-swizzled

    const unsigned short* zp[3] = {zA, zB, zC};
    const int lrv[3] = {lrA, lrB, lrC};

    const int tid = threadIdx.x;
    const int lane = tid & 63;
    const int wave = tid >> 6;
    const int wr = wave >> 2;      // 0..1
    const int wc = wave & 3;       // 0..3
    const int l15 = lane & 15;
    const int lq  = lane >> 4;
    const int c0 = wc * 32 + l15;

    const int r0 = blockIdx.x * 128;
    const int rows = min(128, n - r0);

    const float bn_inv = 0.99999500003749977f;
    float b1c[NREL][2], sc[NREL][2], bec[NREL][2], b2sum[2] = {0.f, 0.f};
#pragma unroll
    for (int rl = 0; rl < NREL; ++rl)
#pragma unroll
        for (int nf = 0; nf < 2; ++nf) {
            const int c = lrv[rl] * H + c0 + nf * 16;
            b1c[rl][nf] = b1g[c]; sc[rl][nf] = g1g[c] * bn_inv;
            bec[rl][nf] = be1g[c]; b2sum[nf] += b2g[c];
        }

    const f32x4 Z4 = {0.f, 0.f, 0.f, 0.f};
    f32x4 acc2[4][2];
#pragma unroll
    for (int rb = 0; rb < 4; ++rb)
#pragma unroll
        for (int nf = 0; nf < 2; ++nf) acc2[rb][nf] = Z4;

#pragma unroll
    for (int rl = 0; rl < NREL; ++rl) {
        const unsigned short* z = zp[rl];
        const unsigned short* wp = wprep + (size_t)lrv[rl] * 32768;

        // ---- GEMM1: z @ W1, A-fragments straight from global ----
        f32x4 acc1[4][2];
#pragma unroll
        for (int rb = 0; rb < 4; ++rb)
#pragma unroll
            for (int nf = 0; nf < 2; ++nf) acc1[rb][nf] = Z4;
#pragma unroll
        for (int kc = 0; kc < 4; ++kc) {
            const int kb = kc * 32 + (lq << 3);
            short8 af[4], wf[2];
#pragma unroll
            for (int rb = 0; rb < 4; ++rb) {
                const int row = wr * 64 + rb * 16 + l15;
                af[rb] = *(const short8*)&z[(size_t)(r0 + row) * H + kb];
            }
#pragma unroll
            for (int nf = 0; nf < 2; ++nf)
                wf[nf] = *(const short8*)&wp[(c0 + nf * 16) * H + kb];
#pragma unroll
            for (int rb = 0; rb < 4; ++rb)
#pragma unroll
                for (int nf = 0; nf < 2; ++nf)
                    acc1[rb][nf] = __builtin_amdgcn_mfma_f32_16x16x32_bf16(
                        af[rb], wf[nf], acc1[rb][nf], 0, 0, 0);
        }
        __syncthreads();  // all waves done reading a1t of previous relation
        // epilogue1: BN+ReLU -> a1t (swizzled)
#pragma unroll
        for (int rb = 0; rb < 4; ++rb)
#pragma unroll
            for (int nf = 0; nf < 2; ++nf) {
                const int col = c0 + nf * 16;
#pragma unroll
                for (int rg = 0; rg < 4; ++rg) {
                    const int row = wr * 64 + rb * 16 + (lq << 2) + rg;
                    float v = fmaxf((acc1[rb][nf][rg] + b1c[rl][nf]) * sc[rl][nf]
                                    + bec[rl][nf], 0.f);
                    a1t[row * H + (col ^ ((row & 7) << 3))] = f2bf(v);
                }
            }
        __syncthreads();  // a1t ready

        // ---- GEMM2: a1t @ W2, C chained in acc2 ----
#pragma unroll
        for (int kc = 0; kc < 4; ++kc) {
            const int kb = kc * 32 + (lq << 3);
            short8 af[4], wf[2];
#pragma unroll
            for (int rb = 0; rb < 4; ++rb) {
                const int row = wr * 64 + rb * 16 + l15;
                af[rb] = *(const short8*)&a1t[row * H + (kb ^ ((row & 7) << 3))];
            }
#pragma unroll
            for (int nf = 0; nf < 2; ++nf)
                wf[nf] = *(const short8*)&wp[16384 + (c0 + nf * 16) * H + kb];
#pragma unroll
            for (int rb = 0; rb < 4; ++rb)
#pragma unroll
                for (int nf = 0; nf < 2; ++nf)
                    acc2[rb][nf] = __builtin_amdgcn_mfma_f32_16x16x32_bf16(
                        af[rb], wf[nf], acc2[rb][nf], 0, 0, 0);
        }
    }

    // ---- final epilogue: hnew = elu(acc2 + sum(b2) + hb) ----
    if (fin) {
#pragma unroll
        for (int rb = 0; rb < 4; ++rb)
#pragma unroll
            for (int nf = 0; nf < 2; ++nf) {
                const int col = c0 + nf * 16;
#pragma unroll
                for (int rg = 0; rg < 4; ++rg) {
                    const int row = wr * 64 + rb * 16 + (lq << 2) + rg;
                    if (row < rows) {
                        const size_t o = (size_t)(r0 + row) * H + col;
                        fout[o] = eluf(acc2[rb][nf][rg] + b2sum[nf]
                                       + bf2f((unsigned int)hb[o]));
                    }
                }
            }
    } else {
        __syncthreads();  // a1t free again
#pragma unroll
        for (int rb = 0; rb < 4; ++rb)
#pragma unroll
            for (int nf = 0; nf < 2; ++nf) {
                const int col = c0 + nf * 16;
#pragma unroll
                for (int rg = 0; rg < 4; ++rg) {
                    const int row = wr * 64 + rb * 16 + (lq << 2) + rg;
                    if (row < rows) {
                        const size_t o = (size_t)(r0 + row) * H + col;
                        a1t[row * H + col] = f2bf(eluf(acc2[rb][nf][rg] + b2sum[nf]
                                                       + bf2f((unsigned int)hb[o])));
                    }
                }
            }
        __syncthreads();
        uint2* d = (uint2*)&hbw[(size_t)r0 * H];
        const uint2* s2 = (const uint2*)a1t;
        for (int idx = tid; idx < rows * 32; idx += 512) d[idx] = s2[idx];
    }
}

static inline int imin(int a, int b) { return a < b ? a : b; }
static inline size_t alignup(size_t x) { return (x + 255) & ~(size_t)255; }

extern "C" void kernel_launch(void* const* d_in, const int* in_sizes, int n_in,
                              void* d_out, int out_size, void* d_ws, size_t ws_size,
                              hipStream_t stream) {
    const float* xin[3] = {(const float*)d_in[0], (const float*)d_in[1], (const float*)d_in[2]};
    const int* src[7]; const int* dst[7]; const float* ea[7]; int E[7];
    for (int r = 0; r < 7; ++r) {
        src[r] = (const int*)d_in[3 + 3 * r];
        dst[r] = (const int*)d_in[4 + 3 * r];
        ea[r]  = (const float*)d_in[5 + 3 * r];
        E[r]   = in_sizes[3 + 3 * r];
    }
    const float* linW[3] = {(const float*)d_in[24], (const float*)d_in[26], (const float*)d_in[28]};
    const float* linb[3] = {(const float*)d_in[25], (const float*)d_in[27], (const float*)d_in[29]};
    const float* eW  = (const float*)d_in[30];
    const float* ebp = (const float*)d_in[31];
    const float* W1  = (const float*)d_in[32];
    const float* b1  = (const float*)d_in[33];
    const float* g1  = (const float*)d_in[34];
    const float* be1 = (const float*)d_in[35];
    const float* W2  = (const float*)d_in[36];
    const float* b2  = (const float*)d_in[37];

    const int NSn[3]  = {in_sizes[0] / 64, in_sizes[1] / 64, in_sizes[2] / 64};
    const int NTOT = NSn[0] + NSn[1] + NSn[2];
    const int noff[3] = {0, NSn[0], NSn[0] + NSn[1]};

    float* fout = (float*)d_out;

    // prefixes
    int eOff[8]; eOff[0] = 0;
    for (int r = 0; r < 7; ++r) eOff[r + 1] = eOff[r] + E[r];
    const int Etot = eOff[7];
    int bOff[8]; bOff[0] = 0;
    for (int r = 0; r < 7; ++r) bOff[r + 1] = bOff[r] + (NSn[DST_T_[r]] + 255) / 256;
    int nOff[8]; nOff[0] = 0;
    for (int r = 0; r < 7; ++r) nOff[r + 1] = nOff[r] + NSn[DST_T_[r]];

    // workspace carve-up
    char* wsb = (char*)d_ws;
    size_t off = 0;
    unsigned short* hb = (unsigned short*)(wsb + off); off = alignup(off + (size_t)NTOT * H * 2);
    unsigned short* zb[7];
    for (int r = 0; r < 7; ++r) {
        int nd = NSn[DST_T_[r]];
        zb[r] = (unsigned short*)(wsb + off); off = alignup(off + (size_t)nd * H * 2);
    }
    unsigned short* wprep = (unsigned short*)(wsb + off); off = alignup(off + (size_t)21 * 32768 * 2);
    int* deg    = (int*)(wsb + off); off = alignup(off + (size_t)bOff[7] * 256 * 4);
    int* cursor = (int*)(wsb + off); off = alignup(off + (size_t)bOff[7] * 256 * 4);
    int* bsum   = (int*)(wsb + off); off = alignup(off + (size_t)bOff[7] * 4 + 256);
    int* ptrs[7]; int* csrs[7]; uint2* ceas[7];
    for (int r = 0; r < 7; ++r) {
        int nd = NSn[DST_T_[r]];
        ptrs[r] = (int*)(wsb + off); off = alignup(off + (size_t)(nd + 1) * 4);
    }
    for (int r = 0; r < 7; ++r) {
        csrs[r] = (int*)(wsb + off); off = alignup(off + (size_t)E[r] * 4);
    }
    for (int r = 0; r < 7; ++r) {
        ceas[r] = (uint2*)(wsb + off); off = alignup(off + (size_t)E[r] * 8);
    }

    // ---- batched CSR build ----
    CsrCtx C;
    for (int r = 0; r < 7; ++r) {
        C.src[r] = src[r]; C.dst[r] = dst[r]; C.ea[r] = ea[r];
        C.csr_src[r] = csrs[r]; C.csr_ea[r] = ceas[r]; C.ptr[r] = ptrs[r];
        C.nd[r] = NSn[DST_T_[r]];
    }
    C.deg = deg; C.cursor = cursor; C.bsum = bsum;
    for (int r = 0; r < 8; ++r) { C.eOff[r] = eOff[r]; C.bOff[r] = bOff[r]; }

    hipMemsetAsync(deg, 0, (size_t)bOff[7] * 256 * 4, stream);
    k_hist_all<<<imin((Etot + 255) / 256, 8192), 256, 0, stream>>>(C, Etot);
    k_scan_partial_all<<<bOff[7], 256, 0, stream>>>(C);
    k_scan_mid_all<<<7, 512, 0, stream>>>(C);
    k_scan_final_all<<<bOff[7], 256, 0, stream>>>(C);
    k_scatter_all<<<imin((Etot + 255) / 256, 8192), 256, 0, stream>>>(C, Etot);
    k_wprep<<<1344, 256, 0, stream>>>(W1, W2, wprep, 21 * 16384);

    // ---- input embeddings (bf16 h) ----
    for (int t = 0; t < 3; ++t) {
        int n = NSn[t];
        k_input_linear<<<imin((n + 15) / 16, 2048), 128, 0, stream>>>(
            xin[t], linW[t], linb[t], hb + (size_t)noff[t] * H, n);
    }

    // ---- agg context ----
    AggCtx A;
    for (int r = 0; r < 7; ++r) {
        A.ptr[r] = ptrs[r]; A.csr_src[r] = csrs[r]; A.csr_ea[r] = ceas[r];
        A.hsrc[r] = hb + (size_t)noff[SRC_T_[r]] * H;
        A.hdst[r] = hb + (size_t)noff[DST_T_[r]] * H;
        A.z[r] = zb[r];
    }
    for (int r = 0; r < 8; ++r) A.nOff[r] = nOff[r];

    // ---- layers ----
    for (int l = 0; l < 3; ++l) {
        const int fin = (l == 2) ? 1 : 0;
        k_aggz_all<<<(nOff[7] + 3) / 4, 256, 0, stream>>>(A, eW, ebp, l, nOff[7]);
        // dst type 0: relations {0,2}
        k_mlp_fused<2><<<(NSn[0] + 127) / 128, 512, 0, stream>>>(
            hb + (size_t)noff[0] * H, hb + (size_t)noff[0] * H,
            fout + (size_t)noff[0] * H, wprep,
            b1, g1, be1, b2, zb[0], zb[2], zb[0],
            l * 7 + 0, l * 7 + 2, 0, NSn[0], fin);
        // dst type 1: relations {1,3,5}
        k_mlp_fused<3><<<(NSn[1] + 127) / 128, 512, 0, stream>>>(
            hb + (size_t)noff[1] * H, hb + (size_t)noff[1] * H,
            fout + (size_t)noff[1] * H, wprep,
            b1, g1, be1, b2, zb[1], zb[3], zb[5],
            l * 7 + 1, l * 7 + 3, l * 7 + 5, NSn[1], fin);
        // dst type 2: relations {4,6}
        k_mlp_fused<2><<<(NSn[2] + 127) / 128, 512, 0, stream>>>(
            hb + (size_t)noff[2] * H, hb + (size_t)noff[2] * H,
            fout + (size_t)noff[2] * H, wprep,
            b1, g1, be1, b2, zb[4], zb[6], zb[4],
            l * 7 + 4, l * 7 + 6, 0, NSn[2], fin);
    }
}

// Round 7
// 1268.816 us; speedup vs baseline: 1.4099x; 1.4099x over previous
//
#include <hip/hip_runtime.h>
#include <math.h>

#define H 128

typedef __attribute__((ext_vector_type(8))) short short8;
typedef __attribute__((ext_vector_type(4))) float f32x4;

static const int SRC_T_[7] = {0, 0, 1, 1, 1, 2, 2};
static const int DST_T_[7] = {0, 1, 0, 1, 2, 1, 2};

__device__ __forceinline__ float eluf(float x) {
    return x > 0.f ? x : (__expf(x) - 1.f);
}
__device__ __forceinline__ unsigned short f2bf(float x) {  // RNE f32->bf16
    union { float f; unsigned int u; } v; v.f = x;
    unsigned int r = v.u + 0x7fffu + ((v.u >> 16) & 1u);
    return (unsigned short)(r >> 16);
}
__device__ __forceinline__ float bf2f(unsigned int u) {
    union { unsigned int u; float f; } v; v.u = u << 16;
    return v.f;
}

// ---------------------------------------------------------------------------
// hb[t] = bf16(elu(x @ W + b)); x:[n,64], W:[64,128]
__global__ __launch_bounds__(128) void k_input_linear(
    const float* __restrict__ x, const float* __restrict__ W,
    const float* __restrict__ b, unsigned short* __restrict__ hb, int n)
{
    __shared__ float Ws[64 * H];
    __shared__ float xs[16 * 64];
    __shared__ unsigned short os[16 * H];
    const int j = threadIdx.x;
    for (int i = j; i < 64 * H; i += 128) Ws[i] = W[i];
    const float bj = b[j];

    for (int r0 = blockIdx.x * 16; r0 < n; r0 += gridDim.x * 16) {
        const int nrows = min(16, n - r0);
        __syncthreads();
        for (int i = j; i < nrows * 64; i += 128) xs[i] = x[(size_t)r0 * 64 + i];
        __syncthreads();
        for (int i = 0; i < nrows; ++i) {
            float acc = bj;
#pragma unroll
            for (int k = 0; k < 64; k += 4) {
                float4 xv = *(const float4*)&xs[i * 64 + k];
                acc += xv.x * Ws[(k + 0) * H + j] + xv.y * Ws[(k + 1) * H + j]
                     + xv.z * Ws[(k + 2) * H + j] + xv.w * Ws[(k + 3) * H + j];
            }
            os[i * H + j] = f2bf(eluf(acc));
        }
        __syncthreads();
        uint2* d = (uint2*)&hb[(size_t)r0 * H];
        const uint2* s2 = (const uint2*)os;
        for (int i = j; i < nrows * 32; i += 128) d[i] = s2[i];
    }
}

// --------------------------- batched CSR build ------------------------------
struct CsrCtx {
    const int* src[7]; const int* dst[7]; const float* ea[7];
    int* csr_src[7]; uint2* csr_ea[7]; int* ptr[7];
    int* deg; int* cursor; int* bsum;
    int eOff[8];   // edge prefix
    int bOff[8];   // 256-block prefix per relation (deg/cursor padded to 256)
    int nd[7];
};

__global__ __launch_bounds__(256) void k_hist_all(CsrCtx C, int Etot)
{
    for (int e = blockIdx.x * 256 + threadIdx.x; e < Etot; e += gridDim.x * 256) {
        int r = 0;
        while (e >= C.eOff[r + 1]) ++r;
        const int le = e - C.eOff[r];
        atomicAdd(&C.deg[(C.bOff[r] << 8) + C.dst[r][le]], 1);
    }
}

__global__ __launch_bounds__(256) void k_scan_partial_all(CsrCtx C)
{
    __shared__ int s[256];
    const int b = blockIdx.x;
    int r = 0;
    while (b >= C.bOff[r + 1]) ++r;
    const int lb = b - C.bOff[r];
    const int tid = threadIdx.x;
    const int idx = lb * 256 + tid;
    s[tid] = idx < C.nd[r] ? C.deg[(C.bOff[r] << 8) + idx] : 0;
    __syncthreads();
    for (int off = 128; off > 0; off >>= 1) {
        if (tid < off) s[tid] += s[tid + off];
        __syncthreads();
    }
    if (tid == 0) C.bsum[b] = s[0];
}

__global__ __launch_bounds__(512) void k_scan_mid_all(CsrCtx C)
{
    __shared__ int s[512];
    const int r = blockIdx.x;
    const int nb = C.bOff[r + 1] - C.bOff[r];
    const int tid = threadIdx.x;
    const int v = tid < nb ? C.bsum[C.bOff[r] + tid] : 0;
    s[tid] = v;
    __syncthreads();
    for (int off = 1; off < 512; off <<= 1) {
        int t = (tid >= off) ? s[tid - off] : 0;
        __syncthreads();
        s[tid] += t;
        __syncthreads();
    }
    if (tid < nb) C.bsum[C.bOff[r] + tid] = s[tid] - v;  // exclusive
    if (tid == nb - 1) C.ptr[r][C.nd[r]] = s[tid];       // total
}

__global__ __launch_bounds__(256) void k_scan_final_all(CsrCtx C)
{
    __shared__ int s[256];
    const int b = blockIdx.x;
    int r = 0;
    while (b >= C.bOff[r + 1]) ++r;
    const int lb = b - C.bOff[r];
    const int tid = threadIdx.x;
    const int idx = lb * 256 + tid;
    const int v = idx < C.nd[r] ? C.deg[(C.bOff[r] << 8) + idx] : 0;
    s[tid] = v;
    __syncthreads();
    for (int off = 1; off < 256; off <<= 1) {
        int t = (tid >= off) ? s[tid - off] : 0;
        __syncthreads();
        s[tid] += t;
        __syncthreads();
    }
    if (idx < C.nd[r]) {
        const int excl = s[tid] - v + C.bsum[b];
        C.ptr[r][idx] = excl;
        C.cursor[(C.bOff[r] << 8) + idx] = excl;
    }
}

__global__ __launch_bounds__(256) void k_scatter_all(CsrCtx C, int Etot)
{
    for (int e = blockIdx.x * 256 + threadIdx.x; e < Etot; e += gridDim.x * 256) {
        int r = 0;
        while (e >= C.eOff[r + 1]) ++r;
        const int le = e - C.eOff[r];
        const int d = C.dst[r][le];
        const int pos = atomicAdd(&C.cursor[(C.bOff[r] << 8) + d], 1);
        C.csr_src[r][pos] = C.src[r][le];
        const float* eap = C.ea[r] + (size_t)3 * le;
        uint2 p;
        p.x = (unsigned int)f2bf(eap[0]) | ((unsigned int)f2bf(eap[1]) << 16);
        p.y = (unsigned int)f2bf(eap[2]);
        C.csr_ea[r][pos] = p;
    }
}

// ---------------------------------------------------------------------------
// Weight prep: W1,W2 [21][128k][128c] f32 -> wp [21][2][128c][128k] bf16
__global__ __launch_bounds__(256) void k_wprep(
    const float* __restrict__ W1, const float* __restrict__ W2,
    unsigned short* __restrict__ wp, int total)
{
    for (int i = blockIdx.x * 256 + threadIdx.x; i < total; i += gridDim.x * 256) {
        int lr = i >> 14, rem = i & 16383;
        int c = rem >> 7, k = rem & 127;
        wp[(size_t)(lr * 2 + 0) * 16384 + rem] = f2bf(W1[(size_t)lr * 16384 + k * H + c]);
        wp[(size_t)(lr * 2 + 1) * 16384 + rem] = f2bf(W2[(size_t)lr * 16384 + k * H + c]);
    }
}

// ---------------------------------------------------------------------------
// Batched gather-aggregate for one layer, all 7 relations:
//   z_r[d] = bf16( hb_dst[d] + sum_e relu(hb_src[csr_src] + ea@eW + eb) )
// 1 node per 64-lane group; 2-edge ILP unroll to overlap gather latency.
struct AggCtx {
    const int* ptr[7]; const int* csr_src[7]; const uint2* csr_ea[7];
    const unsigned short* hsrc[7]; const unsigned short* hdst[7];
    unsigned short* z[7];
    int nOff[8];
};

__global__ __launch_bounds__(256) void k_aggz_all(
    AggCtx A, const float* __restrict__ eW, const float* __restrict__ eb,
    int l, int ntot)
{
    const int g = blockIdx.x * 4 + (threadIdx.x >> 6);
    if (g >= ntot) return;
    int r = 0;
    while (g >= A.nOff[r + 1]) ++r;
    const int d = g - A.nOff[r];
    const int lane = threadIdx.x & 63;
    const int t2 = lane << 1;
    const int lr = l * 7 + r;
    const float* eWr = eW + (size_t)lr * 3 * H;
    const float* ebr = eb + (size_t)lr * H;
    const float w00 = eWr[t2],         w01 = eWr[t2 + 1];
    const float w10 = eWr[H + t2],     w11 = eWr[H + t2 + 1];
    const float w20 = eWr[2 * H + t2], w21 = eWr[2 * H + t2 + 1];
    const float b0 = ebr[t2], b1v = ebr[t2 + 1];

    const int p0 = A.ptr[r][d], p1 = A.ptr[r][d + 1];
    float acc0 = 0.f, acc1 = 0.f;
    const int* cs = A.csr_src[r];
    const uint2* ce = A.csr_ea[r];
    const unsigned short* hs = A.hsrc[r];
    int i = p0;
    for (; i + 1 < p1; i += 2) {
        const int s0 = cs[i], s1 = cs[i + 1];
        const uint2 e0 = ce[i], e1 = ce[i + 1];
        const unsigned int hv0 = ((const unsigned int*)&hs[(size_t)s0 * H])[lane];
        const unsigned int hv1 = ((const unsigned int*)&hs[(size_t)s1 * H])[lane];
        const float a00 = bf2f(e0.x & 0xffffu), a01 = bf2f(e0.x >> 16), a02 = bf2f(e0.y & 0xffffu);
        const float a10 = bf2f(e1.x & 0xffffu), a11 = bf2f(e1.x >> 16), a12 = bf2f(e1.y & 0xffffu);
        acc0 += fmaxf(bf2f(hv0 & 0xffffu) + a00 * w00 + a01 * w10 + a02 * w20 + b0, 0.f)
              + fmaxf(bf2f(hv1 & 0xffffu) + a10 * w00 + a11 * w10 + a12 * w20 + b0, 0.f);
        acc1 += fmaxf(bf2f(hv0 >> 16) + a00 * w01 + a01 * w11 + a02 * w21 + b1v, 0.f)
              + fmaxf(bf2f(hv1 >> 16) + a10 * w01 + a11 * w11 + a12 * w21 + b1v, 0.f);
    }
    if (i < p1) {
        const int s = cs[i];
        const uint2 ep = ce[i];
        const float a0 = bf2f(ep.x & 0xffffu);
        const float a1 = bf2f(ep.x >> 16);
        const float a2 = bf2f(ep.y & 0xffffu);
        const unsigned int hv = ((const unsigned int*)&hs[(size_t)s * H])[lane];
        acc0 += fmaxf(bf2f(hv & 0xffffu) + a0 * w00 + a1 * w10 + a2 * w20 + b0, 0.f);
        acc1 += fmaxf(bf2f(hv >> 16)     + a0 * w01 + a1 * w11 + a2 * w21 + b1v, 0.f);
    }
    const unsigned int hd = ((const unsigned int*)&A.hdst[r][(size_t)d * H])[lane];
    acc0 += bf2f(hd & 0xffffu);
    acc1 += bf2f(hd >> 16);
    ((unsigned int*)A.z[r])[d * 64 + lane] =
        (unsigned int)f2bf(acc0) | ((unsigned int)f2bf(acc1) << 16);
}

// ---------------------------------------------------------------------------
// Fused multi-relation MFMA MLP for one dst type, z precomputed bf16 in global:
//   hnew = elu( sum_rel (relu(z_rel@W1*bn+..)@W2 + b2) + hb )
// z staged per relation into XOR-swizzled LDS (zt); a1t also in LDS. 64 KB.
template<int NREL>
__global__ __launch_bounds__(512, 4) void k_mlp_fused(
    const unsigned short* __restrict__ hb, unsigned short* __restrict__ hbw,
    float* __restrict__ fout,
    const unsigned short* __restrict__ wprep,
    const float* __restrict__ b1g, const float* __restrict__ g1g,
    const float* __restrict__ be1g, const float* __restrict__ b2g,
    const unsigned short* __restrict__ zA, const unsigned short* __restrict__ zB,
    const unsigned short* __restrict__ zC,
    int lrA, int lrB, int lrC, int n, int fin)
{
    __shared__ unsigned short zt[128 * H];   // 32 KB, XOR-swizzled
    __shared__ unsigned short a1t[128 * H];  // 32 KB, XOR-swizzled

    const unsigned short* zp[3] = {zA, zB, zC};
    const int lrv[3] = {lrA, lrB, lrC};

    const int tid = threadIdx.x;
    const int lane = tid & 63;
    const int wave = tid >> 6;
    const int wr = wave >> 2;      // 0..1
    const int wc = wave & 3;       // 0..3
    const int l15 = lane & 15;
    const int lq  = lane >> 4;
    const int c0 = wc * 32 + l15;

    const int r0 = blockIdx.x * 128;
    const int rows = min(128, n - r0);

    const float bn_inv = 0.99999500003749977f;
    float b1c[NREL][2], sc[NREL][2], bec[NREL][2], b2sum[2] = {0.f, 0.f};
#pragma unroll
    for (int rl = 0; rl < NREL; ++rl)
#pragma unroll
        for (int nf = 0; nf < 2; ++nf) {
            const int c = lrv[rl] * H + c0 + nf * 16;
            b1c[rl][nf] = b1g[c]; sc[rl][nf] = g1g[c] * bn_inv;
            bec[rl][nf] = be1g[c]; b2sum[nf] += b2g[c];
        }

    const f32x4 Z4 = {0.f, 0.f, 0.f, 0.f};
    f32x4 acc2[4][2];
#pragma unroll
    for (int rb = 0; rb < 4; ++rb)
#pragma unroll
        for (int nf = 0; nf < 2; ++nf) acc2[rb][nf] = Z4;

#pragma unroll
    for (int rl = 0; rl < NREL; ++rl) {
        const unsigned short* z = zp[rl];
        const unsigned short* wp = wprep + (size_t)lrv[rl] * 32768;

        // ---- stage z tile -> zt (swizzled); pure copy, no math ----
        if (rows == 128) {
            uint4 v[4];
#pragma unroll
            for (int it = 0; it < 4; ++it) {
                const int idx = tid + it * 512;
                const int row = idx >> 4, cg = (idx & 15) << 3;
                v[it] = *(const uint4*)&z[(size_t)(r0 + row) * H + cg];
            }
#pragma unroll
            for (int it = 0; it < 4; ++it) {
                const int idx = tid + it * 512;
                const int row = idx >> 4, cg = (idx & 15) << 3;
                *(uint4*)&zt[row * H + (cg ^ ((row & 7) << 3))] = v[it];
            }
        } else {
            for (int idx = tid; idx < rows * 16; idx += 512) {
                const int row = idx >> 4, cg = (idx & 15) << 3;
                uint4 v = *(const uint4*)&z[(size_t)(r0 + row) * H + cg];
                *(uint4*)&zt[row * H + (cg ^ ((row & 7) << 3))] = v;
            }
        }
        __syncthreads();  // A: zt ready (also fences prev GEMM1's zt reads)

        // ---- GEMM1: zt @ W1 ----
        f32x4 acc1[4][2];
#pragma unroll
        for (int rb = 0; rb < 4; ++rb)
#pragma unroll
            for (int nf = 0; nf < 2; ++nf) acc1[rb][nf] = Z4;
#pragma unroll
        for (int kc = 0; kc < 4; ++kc) {
            const int kb = kc * 32 + (lq << 3);
            short8 af[4], wf[2];
#pragma unroll
            for (int rb = 0; rb < 4; ++rb) {
                const int row = wr * 64 + rb * 16 + l15;
                af[rb] = *(const short8*)&zt[row * H + (kb ^ ((row & 7) << 3))];
            }
#pragma unroll
            for (int nf = 0; nf < 2; ++nf)
                wf[nf] = *(const short8*)&wp[(c0 + nf * 16) * H + kb];
#pragma unroll
            for (int rb = 0; rb < 4; ++rb)
#pragma unroll
                for (int nf = 0; nf < 2; ++nf)
                    acc1[rb][nf] = __builtin_amdgcn_mfma_f32_16x16x32_bf16(
                        af[rb], wf[nf], acc1[rb][nf], 0, 0, 0);
        }
        // epilogue1: BN+ReLU -> a1t (swizzled)
#pragma unroll
        for (int rb = 0; rb < 4; ++rb)
#pragma unroll
            for (int nf = 0; nf < 2; ++nf) {
                const int col = c0 + nf * 16;
#pragma unroll
                for (int rg = 0; rg < 4; ++rg) {
                    const int row = wr * 64 + rb * 16 + (lq << 2) + rg;
                    float v = fmaxf((acc1[rb][nf][rg] + b1c[rl][nf]) * sc[rl][nf]
                                    + bec[rl][nf], 0.f);
                    a1t[row * H + (col ^ ((row & 7) << 3))] = f2bf(v);
                }
            }
        __syncthreads();  // B: a1t ready

        // ---- GEMM2: a1t @ W2, C chained in acc2 ----
#pragma unroll
        for (int kc = 0; kc < 4; ++kc) {
            const int kb = kc * 32 + (lq << 3);
            short8 af[4], wf[2];
#pragma unroll
            for (int rb = 0; rb < 4; ++rb) {
                const int row = wr * 64 + rb * 16 + l15;
                af[rb] = *(const short8*)&a1t[row * H + (kb ^ ((row & 7) << 3))];
            }
#pragma unroll
            for (int nf = 0; nf < 2; ++nf)
                wf[nf] = *(const short8*)&wp[16384 + (c0 + nf * 16) * H + kb];
#pragma unroll
            for (int rb = 0; rb < 4; ++rb)
#pragma unroll
                for (int nf = 0; nf < 2; ++nf)
                    acc2[rb][nf] = __builtin_amdgcn_mfma_f32_16x16x32_bf16(
                        af[rb], wf[nf], acc2[rb][nf], 0, 0, 0);
        }
    }

    // ---- final epilogue: hnew = elu(acc2 + sum(b2) + hb) ----
    if (fin) {
#pragma unroll
        for (int rb = 0; rb < 4; ++rb)
#pragma unroll
            for (int nf = 0; nf < 2; ++nf) {
                const int col = c0 + nf * 16;
#pragma unroll
                for (int rg = 0; rg < 4; ++rg) {
                    const int row = wr * 64 + rb * 16 + (lq << 2) + rg;
                    if (row < rows) {
                        const size_t o = (size_t)(r0 + row) * H + col;
                        fout[o] = eluf(acc2[rb][nf][rg] + b2sum[nf]
                                       + bf2f((unsigned int)hb[o]));
                    }
                }
            }
    } else {
        __syncthreads();  // all GEMM2 reads of a1t done
#pragma unroll
        for (int rb = 0; rb < 4; ++rb)
#pragma unroll
            for (int nf = 0; nf < 2; ++nf) {
                const int col = c0 + nf * 16;
#pragma unroll
                for (int rg = 0; rg < 4; ++rg) {
                    const int row = wr * 64 + rb * 16 + (lq << 2) + rg;
                    if (row < rows) {
                        const size_t o = (size_t)(r0 + row) * H + col;
                        a1t[row * H + col] = f2bf(eluf(acc2[rb][nf][rg] + b2sum[nf]
                                                       + bf2f((unsigned int)hb[o])));
                    }
                }
            }
        __syncthreads();
        uint2* d = (uint2*)&hbw[(size_t)r0 * H];
        const uint2* s2 = (const uint2*)a1t;
        for (int idx = tid; idx < rows * 32; idx += 512) d[idx] = s2[idx];
    }
}

static inline int imin(int a, int b) { return a < b ? a : b; }
static inline size_t alignup(size_t x) { return (x + 255) & ~(size_t)255; }

extern "C" void kernel_launch(void* const* d_in, const int* in_sizes, int n_in,
                              void* d_out, int out_size, void* d_ws, size_t ws_size,
                              hipStream_t stream) {
    const float* xin[3] = {(const float*)d_in[0], (const float*)d_in[1], (const float*)d_in[2]};
    const int* src[7]; const int* dst[7]; const float* ea[7]; int E[7];
    for (int r = 0; r < 7; ++r) {
        src[r] = (const int*)d_in[3 + 3 * r];
        dst[r] = (const int*)d_in[4 + 3 * r];
        ea[r]  = (const float*)d_in[5 + 3 * r];
        E[r]   = in_sizes[3 + 3 * r];
    }
    const float* linW[3] = {(const float*)d_in[24], (const float*)d_in[26], (const float*)d_in[28]};
    const float* linb[3] = {(const float*)d_in[25], (const float*)d_in[27], (const float*)d_in[29]};
    const float* eW  = (const float*)d_in[30];
    const float* ebp = (const float*)d_in[31];
    const float* W1  = (const float*)d_in[32];
    const float* b1  = (const float*)d_in[33];
    const float* g1  = (const float*)d_in[34];
    const float* be1 = (const float*)d_in[35];
    const float* W2  = (const float*)d_in[36];
    const float* b2  = (const float*)d_in[37];

    const int NSn[3]  = {in_sizes[0] / 64, in_sizes[1] / 64, in_sizes[2] / 64};
    const int NTOT = NSn[0] + NSn[1] + NSn[2];
    const int noff[3] = {0, NSn[0], NSn[0] + NSn[1]};

    float* fout = (float*)d_out;

    // prefixes
    int eOff[8]; eOff[0] = 0;
    for (int r = 0; r < 7; ++r) eOff[r + 1] = eOff[r] + E[r];
    const int Etot = eOff[7];
    int bOff[8]; bOff[0] = 0;
    for (int r = 0; r < 7; ++r) bOff[r + 1] = bOff[r] + (NSn[DST_T_[r]] + 255) / 256;
    int nOff[8]; nOff[0] = 0;
    for (int r = 0; r < 7; ++r) nOff[r + 1] = nOff[r] + NSn[DST_T_[r]];

    // workspace carve-up
    char* wsb = (char*)d_ws;
    size_t off = 0;
    unsigned short* hb = (unsigned short*)(wsb + off); off = alignup(off + (size_t)NTOT * H * 2);
    unsigned short* zb[7];
    for (int r = 0; r < 7; ++r) {
        int nd = NSn[DST_T_[r]];
        zb[r] = (unsigned short*)(wsb + off); off = alignup(off + (size_t)nd * H * 2);
    }
    unsigned short* wprep = (unsigned short*)(wsb + off); off = alignup(off + (size_t)21 * 32768 * 2);
    int* deg    = (int*)(wsb + off); off = alignup(off + (size_t)bOff[7] * 256 * 4);
    int* cursor = (int*)(wsb + off); off = alignup(off + (size_t)bOff[7] * 256 * 4);
    int* bsum   = (int*)(wsb + off); off = alignup(off + (size_t)bOff[7] * 4 + 256);
    int* ptrs[7]; int* csrs[7]; uint2* ceas[7];
    for (int r = 0; r < 7; ++r) {
        int nd = NSn[DST_T_[r]];
        ptrs[r] = (int*)(wsb + off); off = alignup(off + (size_t)(nd + 1) * 4);
    }
    for (int r = 0; r < 7; ++r) {
        csrs[r] = (int*)(wsb + off); off = alignup(off + (size_t)E[r] * 4);
    }
    for (int r = 0; r < 7; ++r) {
        ceas[r] = (uint2*)(wsb + off); off = alignup(off + (size_t)E[r] * 8);
    }

    // ---- batched CSR build ----
    CsrCtx C;
    for (int r = 0; r < 7; ++r) {
        C.src[r] = src[r]; C.dst[r] = dst[r]; C.ea[r] = ea[r];
        C.csr_src[r] = csrs[r]; C.csr_ea[r] = ceas[r]; C.ptr[r] = ptrs[r];
        C.nd[r] = NSn[DST_T_[r]];
    }
    C.deg = deg; C.cursor = cursor; C.bsum = bsum;
    for (int r = 0; r < 8; ++r) { C.eOff[r] = eOff[r]; C.bOff[r] = bOff[r]; }

    hipMemsetAsync(deg, 0, (size_t)bOff[7] * 256 * 4, stream);
    k_hist_all<<<imin((Etot + 255) / 256, 8192), 256, 0, stream>>>(C, Etot);
    k_scan_partial_all<<<bOff[7], 256, 0, stream>>>(C);
    k_scan_mid_all<<<7, 512, 0, stream>>>(C);
    k_scan_final_all<<<bOff[7], 256, 0, stream>>>(C);
    k_scatter_all<<<imin((Etot + 255) / 256, 8192), 256, 0, stream>>>(C, Etot);
    k_wprep<<<1344, 256, 0, stream>>>(W1, W2, wprep, 21 * 16384);

    // ---- input embeddings (bf16 h) ----
    for (int t = 0; t < 3; ++t) {
        int n = NSn[t];
        k_input_linear<<<imin((n + 15) / 16, 2048), 128, 0, stream>>>(
            xin[t], linW[t], linb[t], hb + (size_t)noff[t] * H, n);
    }

    // ---- agg context ----
    AggCtx A;
    for (int r = 0; r < 7; ++r) {
        A.ptr[r] = ptrs[r]; A.csr_src[r] = csrs[r]; A.csr_ea[r] = ceas[r];
        A.hsrc[r] = hb + (size_t)noff[SRC_T_[r]] * H;
        A.hdst[r] = hb + (size_t)noff[DST_T_[r]] * H;
        A.z[r] = zb[r];
    }
    for (int r = 0; r < 8; ++r) A.nOff[r] = nOff[r];

    // ---- layers ----
    for (int l = 0; l < 3; ++l) {
        const int fin = (l == 2) ? 1 : 0;
        k_aggz_all<<<(nOff[7] + 3) / 4, 256, 0, stream>>>(A, eW, ebp, l, nOff[7]);
        // dst type 0: relations {0,2}
        k_mlp_fused<2><<<(NSn[0] + 127) / 128, 512, 0, stream>>>(
            hb + (size_t)noff[0] * H, hb + (size_t)noff[0] * H,
            fout + (size_t)noff[0] * H, wprep,
            b1, g1, be1, b2, zb[0], zb[2], zb[0],
            l * 7 + 0, l * 7 + 2, 0, NSn[0], fin);
        // dst type 1: relations {1,3,5}
        k_mlp_fused<3><<<(NSn[1] + 127) / 128, 512, 0, stream>>>(
            hb + (size_t)noff[1] * H, hb + (size_t)noff[1] * H,
            fout + (size_t)noff[1] * H, wprep,
            b1, g1, be1, b2, zb[1], zb[3], zb[5],
            l * 7 + 1, l * 7 + 3, l * 7 + 5, NSn[1], fin);
        // dst type 2: relations {4,6}
        k_mlp_fused<2><<<(NSn[2] + 127) / 128, 512, 0, stream>>>(
            hb + (size_t)noff[2] * H, hb + (size_t)noff[2] * H,
            fout + (size_t)noff[2] * H, wprep,
            b1, g1, be1, b2, zb[4], zb[6], zb[4],
            l * 7 + 4, l * 7 + 6, 0, NSn[2], fin);
    }
}

// Round 8
// 1211.401 us; speedup vs baseline: 1.4767x; 1.0474x over previous
//
#include <hip/hip_runtime.h>
#include <math.h>

#define H 128

typedef __attribute__((ext_vector_type(8))) short short8;
typedef __attribute__((ext_vector_type(4))) float f32x4;

static const int SRC_T_[7] = {0, 0, 1, 1, 1, 2, 2};
static const int DST_T_[7] = {0, 1, 0, 1, 2, 1, 2};

__device__ __forceinline__ float eluf(float x) {
    return x > 0.f ? x : (__expf(x) - 1.f);
}
__device__ __forceinline__ unsigned short f2bf(float x) {  // RNE f32->bf16
    union { float f; unsigned int u; } v; v.f = x;
    unsigned int r = v.u + 0x7fffu + ((v.u >> 16) & 1u);
    return (unsigned short)(r >> 16);
}
__device__ __forceinline__ float bf2f(unsigned int u) {
    union { unsigned int u; float f; } v; v.u = u << 16;
    return v.f;
}

// ---------------------------------------------------------------------------
// hb[t] = bf16(elu(x @ W + b)); x:[n,64], W:[64,128]
__global__ __launch_bounds__(128) void k_input_linear(
    const float* __restrict__ x, const float* __restrict__ W,
    const float* __restrict__ b, unsigned short* __restrict__ hb, int n)
{
    __shared__ float Ws[64 * H];
    __shared__ float xs[16 * 64];
    __shared__ unsigned short os[16 * H];
    const int j = threadIdx.x;
    for (int i = j; i < 64 * H; i += 128) Ws[i] = W[i];
    const float bj = b[j];

    for (int r0 = blockIdx.x * 16; r0 < n; r0 += gridDim.x * 16) {
        const int nrows = min(16, n - r0);
        __syncthreads();
        for (int i = j; i < nrows * 64; i += 128) xs[i] = x[(size_t)r0 * 64 + i];
        __syncthreads();
        for (int i = 0; i < nrows; ++i) {
            float acc = bj;
#pragma unroll
            for (int k = 0; k < 64; k += 4) {
                float4 xv = *(const float4*)&xs[i * 64 + k];
                acc += xv.x * Ws[(k + 0) * H + j] + xv.y * Ws[(k + 1) * H + j]
                     + xv.z * Ws[(k + 2) * H + j] + xv.w * Ws[(k + 3) * H + j];
            }
            os[i * H + j] = f2bf(eluf(acc));
        }
        __syncthreads();
        uint2* d = (uint2*)&hb[(size_t)r0 * H];
        const uint2* s2 = (const uint2*)os;
        for (int i = j; i < nrows * 32; i += 128) d[i] = s2[i];
    }
}

// --------------------------- batched CSR build ------------------------------
struct CsrCtx {
    const int* src[7]; const int* dst[7]; const float* ea[7];
    int* csr_src[7]; uint2* csr_ea[7]; int* ptr[7];
    int* deg; int* cursor; int* bsum;
    int eOff[8];
    int bOff[8];
    int nd[7];
};

__global__ __launch_bounds__(256) void k_hist_all(CsrCtx C, int Etot)
{
    for (int e = blockIdx.x * 256 + threadIdx.x; e < Etot; e += gridDim.x * 256) {
        int r = 0;
        while (e >= C.eOff[r + 1]) ++r;
        const int le = e - C.eOff[r];
        atomicAdd(&C.deg[(C.bOff[r] << 8) + C.dst[r][le]], 1);
    }
}

__global__ __launch_bounds__(256) void k_scan_partial_all(CsrCtx C)
{
    __shared__ int s[256];
    const int b = blockIdx.x;
    int r = 0;
    while (b >= C.bOff[r + 1]) ++r;
    const int lb = b - C.bOff[r];
    const int tid = threadIdx.x;
    const int idx = lb * 256 + tid;
    s[tid] = idx < C.nd[r] ? C.deg[(C.bOff[r] << 8) + idx] : 0;
    __syncthreads();
    for (int off = 128; off > 0; off >>= 1) {
        if (tid < off) s[tid] += s[tid + off];
        __syncthreads();
    }
    if (tid == 0) C.bsum[b] = s[0];
}

__global__ __launch_bounds__(512) void k_scan_mid_all(CsrCtx C)
{
    __shared__ int s[512];
    const int r = blockIdx.x;
    const int nb = C.bOff[r + 1] - C.bOff[r];
    const int tid = threadIdx.x;
    const int v = tid < nb ? C.bsum[C.bOff[r] + tid] : 0;
    s[tid] = v;
    __syncthreads();
    for (int off = 1; off < 512; off <<= 1) {
        int t = (tid >= off) ? s[tid - off] : 0;
        __syncthreads();
        s[tid] += t;
        __syncthreads();
    }
    if (tid < nb) C.bsum[C.bOff[r] + tid] = s[tid] - v;
    if (tid == nb - 1) C.ptr[r][C.nd[r]] = s[tid];
}

__global__ __launch_bounds__(256) void k_scan_final_all(CsrCtx C)
{
    __shared__ int s[256];
    const int b = blockIdx.x;
    int r = 0;
    while (b >= C.bOff[r + 1]) ++r;
    const int lb = b - C.bOff[r];
    const int tid = threadIdx.x;
    const int idx = lb * 256 + tid;
    const int v = idx < C.nd[r] ? C.deg[(C.bOff[r] << 8) + idx] : 0;
    s[tid] = v;
    __syncthreads();
    for (int off = 1; off < 256; off <<= 1) {
        int t = (tid >= off) ? s[tid - off] : 0;
        __syncthreads();
        s[tid] += t;
        __syncthreads();
    }
    if (idx < C.nd[r]) {
        const int excl = s[tid] - v + C.bsum[b];
        C.ptr[r][idx] = excl;
        C.cursor[(C.bOff[r] << 8) + idx] = excl;
    }
}

__global__ __launch_bounds__(256) void k_scatter_all(CsrCtx C, int Etot)
{
    for (int e = blockIdx.x * 256 + threadIdx.x; e < Etot; e += gridDim.x * 256) {
        int r = 0;
        while (e >= C.eOff[r + 1]) ++r;
        const int le = e - C.eOff[r];
        const int d = C.dst[r][le];
        const int pos = atomicAdd(&C.cursor[(C.bOff[r] << 8) + d], 1);
        C.csr_src[r][pos] = C.src[r][le];
        const float* eap = C.ea[r] + (size_t)3 * le;
        uint2 p;
        p.x = (unsigned int)f2bf(eap[0]) | ((unsigned int)f2bf(eap[1]) << 16);
        p.y = (unsigned int)f2bf(eap[2]);
        C.csr_ea[r][pos] = p;
    }
}

// ---------------------------------------------------------------------------
// Weight prep: W1,W2 [21][128k][128c] f32 -> wp [21][2][128c][128k] bf16
__global__ __launch_bounds__(256) void k_wprep(
    const float* __restrict__ W1, const float* __restrict__ W2,
    unsigned short* __restrict__ wp, int total)
{
    for (int i = blockIdx.x * 256 + threadIdx.x; i < total; i += gridDim.x * 256) {
        int lr = i >> 14, rem = i & 16383;
        int c = rem >> 7, k = rem & 127;
        wp[(size_t)(lr * 2 + 0) * 16384 + rem] = f2bf(W1[(size_t)lr * 16384 + k * H + c]);
        wp[(size_t)(lr * 2 + 1) * 16384 + rem] = f2bf(W2[(size_t)lr * 16384 + k * H + c]);
    }
}

// ---------------------------------------------------------------------------
// Batched gather-aggregate, half-wave edge-parallel:
//   z_r[d] = bf16( hb_dst[d] + sum_e relu(hb_src + ea@eW + eb) )
// lanes 0-31 edge i, lanes 32-63 edge i+1; 4 cols/lane; 2 pairs in flight.
struct AggCtx {
    const int* ptr[7]; const int* csr_src[7]; const uint2* csr_ea[7];
    const unsigned short* hsrc[7]; const unsigned short* hdst[7];
    unsigned short* z[7];
    int nOff[8];
};

__global__ __launch_bounds__(256) void k_aggz_all(
    AggCtx A, const float* __restrict__ eW, const float* __restrict__ eb,
    int l, int ntot)
{
    const int g = blockIdx.x * 4 + (threadIdx.x >> 6);
    if (g >= ntot) return;
    int r = 0;
    while (g >= A.nOff[r + 1]) ++r;
    const int d = g - A.nOff[r];
    const int lane = threadIdx.x & 63;
    const int half = lane >> 5;
    const int c4 = (lane & 31) << 2;   // 4 cols per lane
    const int lr = l * 7 + r;
    const float* eWr = eW + (size_t)lr * 3 * H;
    const float* ebr = eb + (size_t)lr * H;
    float w0[4], w1[4], w2[4], bb[4];
#pragma unroll
    for (int q = 0; q < 4; ++q) {
        w0[q] = eWr[c4 + q]; w1[q] = eWr[H + c4 + q]; w2[q] = eWr[2 * H + c4 + q];
        bb[q] = ebr[c4 + q];
    }

    const int p0 = A.ptr[r][d], p1 = A.ptr[r][d + 1];
    const int* cs = A.csr_src[r];
    const uint2* ce = A.csr_ea[r];
    const unsigned short* hs = A.hsrc[r];
    float a0 = 0.f, a1 = 0.f, a2 = 0.f, a3 = 0.f;

    for (int i = p0; i < p1; i += 4) {
        const int iA = i + half;
        const int iB = i + 2 + half;
        const bool vA = iA < p1, vB = iB < p1;
        const int cA = vA ? iA : i;
        const int cB = vB ? iB : i;
        const int sA = cs[cA], sB = cs[cB];
        const uint2 eA = ce[cA], eB = ce[cB];
        const uint2 hA = *(const uint2*)&hs[(size_t)sA * H + c4];
        const uint2 hB = *(const uint2*)&hs[(size_t)sB * H + c4];
        {
            const float e0 = bf2f(eA.x & 0xffffu), e1 = bf2f(eA.x >> 16), e2 = bf2f(eA.y & 0xffffu);
            const float m0 = fmaxf(bf2f(hA.x & 0xffffu) + e0 * w0[0] + e1 * w1[0] + e2 * w2[0] + bb[0], 0.f);
            const float m1 = fmaxf(bf2f(hA.x >> 16)     + e0 * w0[1] + e1 * w1[1] + e2 * w2[1] + bb[1], 0.f);
            const float m2 = fmaxf(bf2f(hA.y & 0xffffu) + e0 * w0[2] + e1 * w1[2] + e2 * w2[2] + bb[2], 0.f);
            const float m3 = fmaxf(bf2f(hA.y >> 16)     + e0 * w0[3] + e1 * w1[3] + e2 * w2[3] + bb[3], 0.f);
            if (vA) { a0 += m0; a1 += m1; a2 += m2; a3 += m3; }
        }
        {
            const float e0 = bf2f(eB.x & 0xffffu), e1 = bf2f(eB.x >> 16), e2 = bf2f(eB.y & 0xffffu);
            const float m0 = fmaxf(bf2f(hB.x & 0xffffu) + e0 * w0[0] + e1 * w1[0] + e2 * w2[0] + bb[0], 0.f);
            const float m1 = fmaxf(bf2f(hB.x >> 16)     + e0 * w0[1] + e1 * w1[1] + e2 * w2[1] + bb[1], 0.f);
            const float m2 = fmaxf(bf2f(hB.y & 0xffffu) + e0 * w0[2] + e1 * w1[2] + e2 * w2[2] + bb[2], 0.f);
            const float m3 = fmaxf(bf2f(hB.y >> 16)     + e0 * w0[3] + e1 * w1[3] + e2 * w2[3] + bb[3], 0.f);
            if (vB) { a0 += m0; a1 += m1; a2 += m2; a3 += m3; }
        }
    }
    // combine halves (lane ^ 32)
    a0 += __shfl_xor(a0, 32, 64);
    a1 += __shfl_xor(a1, 32, 64);
    a2 += __shfl_xor(a2, 32, 64);
    a3 += __shfl_xor(a3, 32, 64);
    if (half == 0) {
        const uint2 hd = *(const uint2*)&A.hdst[r][(size_t)d * H + c4];
        a0 += bf2f(hd.x & 0xffffu); a1 += bf2f(hd.x >> 16);
        a2 += bf2f(hd.y & 0xffffu); a3 += bf2f(hd.y >> 16);
        uint2 o;
        o.x = (unsigned int)f2bf(a0) | ((unsigned int)f2bf(a1) << 16);
        o.y = (unsigned int)f2bf(a2) | ((unsigned int)f2bf(a3) << 16);
        *(uint2*)&A.z[r][(size_t)d * H + c4] = o;
    }
}

// ---------------------------------------------------------------------------
// One dispatch per layer: all 3 dst-types' fused MLPs.
//   hnew = elu( sum_rel (relu(z_rel@W1*bn+..)@W2 + b2) + hb )
struct MlpCtx {
    const unsigned short* z[3][3];
    int lr[3][3];
    int nrel[3];
    int gend[3];     // cumulative block-range ends per type
    int noffH[3];    // node offset * H
    int n[3];
};

__global__ __launch_bounds__(512, 4) void k_mlp_all(
    MlpCtx M, const unsigned short* __restrict__ hb,
    unsigned short* __restrict__ hbw, float* __restrict__ fout,
    const unsigned short* __restrict__ wprep,
    const float* __restrict__ b1g, const float* __restrict__ g1g,
    const float* __restrict__ be1g, const float* __restrict__ b2g, int fin)
{
    __shared__ unsigned short zt[128 * H];   // 32 KB, XOR-swizzled
    __shared__ unsigned short a1t[128 * H];  // 32 KB, XOR-swizzled

    const int b = blockIdx.x;
    const int t = (b >= M.gend[0] ? 1 : 0) + (b >= M.gend[1] ? 1 : 0);
    const int lb = b - (t == 0 ? 0 : M.gend[t - 1]);
    const int n = M.n[t];
    const int nrel = M.nrel[t];
    const unsigned short* hbp = hb + (size_t)M.noffH[t];

    const int tid = threadIdx.x;
    const int lane = tid & 63;
    const int wave = tid >> 6;
    const int wr = wave >> 2;
    const int wc = wave & 3;
    const int l15 = lane & 15;
    const int lq  = lane >> 4;
    const int c0 = wc * 32 + l15;

    const int r0 = lb * 128;
    const int rows = min(128, n - r0);

    const float bn_inv = 0.99999500003749977f;
    const f32x4 Z4 = {0.f, 0.f, 0.f, 0.f};
    f32x4 acc2[4][2];
#pragma unroll
    for (int rb = 0; rb < 4; ++rb)
#pragma unroll
        for (int nf = 0; nf < 2; ++nf) acc2[rb][nf] = Z4;
    float b2s0 = 0.f, b2s1 = 0.f;

    for (int rl = 0; rl < nrel; ++rl) {
        const unsigned short* z = M.z[t][rl];
        const int lr = M.lr[t][rl];
        const unsigned short* wp = wprep + (size_t)lr * 32768;
        const float b1c0 = b1g[lr * H + c0],            b1c1 = b1g[lr * H + c0 + 16];
        const float sc0  = g1g[lr * H + c0] * bn_inv,   sc1  = g1g[lr * H + c0 + 16] * bn_inv;
        const float be0  = be1g[lr * H + c0],           be1v = be1g[lr * H + c0 + 16];
        b2s0 += b2g[lr * H + c0]; b2s1 += b2g[lr * H + c0 + 16];

        // ---- stage z tile -> zt (swizzled) ----
        if (rows == 128) {
            uint4 v[4];
#pragma unroll
            for (int it = 0; it < 4; ++it) {
                const int idx = tid + it * 512;
                const int row = idx >> 4, cg = (idx & 15) << 3;
                v[it] = *(const uint4*)&z[(size_t)(r0 + row) * H + cg];
            }
#pragma unroll
            for (int it = 0; it < 4; ++it) {
                const int idx = tid + it * 512;
                const int row = idx >> 4, cg = (idx & 15) << 3;
                *(uint4*)&zt[row * H + (cg ^ ((row & 7) << 3))] = v[it];
            }
        } else {
            for (int idx = tid; idx < rows * 16; idx += 512) {
                const int row = idx >> 4, cg = (idx & 15) << 3;
                uint4 v = *(const uint4*)&z[(size_t)(r0 + row) * H + cg];
                *(uint4*)&zt[row * H + (cg ^ ((row & 7) << 3))] = v;
            }
        }
        __syncthreads();  // A: zt ready

        // ---- GEMM1: zt @ W1 ----
        f32x4 acc1[4][2];
#pragma unroll
        for (int rb = 0; rb < 4; ++rb)
#pragma unroll
            for (int nf = 0; nf < 2; ++nf) acc1[rb][nf] = Z4;
#pragma unroll
        for (int kc = 0; kc < 4; ++kc) {
            const int kb = kc * 32 + (lq << 3);
            short8 af[4], wf[2];
#pragma unroll
            for (int rb = 0; rb < 4; ++rb) {
                const int row = wr * 64 + rb * 16 + l15;
                af[rb] = *(const short8*)&zt[row * H + (kb ^ ((row & 7) << 3))];
            }
#pragma unroll
            for (int nf = 0; nf < 2; ++nf)
                wf[nf] = *(const short8*)&wp[(c0 + nf * 16) * H + kb];
#pragma unroll
            for (int rb = 0; rb < 4; ++rb)
#pragma unroll
                for (int nf = 0; nf < 2; ++nf)
                    acc1[rb][nf] = __builtin_amdgcn_mfma_f32_16x16x32_bf16(
                        af[rb], wf[nf], acc1[rb][nf], 0, 0, 0);
        }
        // epilogue1: BN+ReLU -> a1t (swizzled)
#pragma unroll
        for (int rb = 0; rb < 4; ++rb)
#pragma unroll
            for (int nf = 0; nf < 2; ++nf) {
                const int col = c0 + nf * 16;
                const float b1c = nf == 0 ? b1c0 : b1c1;
                const float scv = nf == 0 ? sc0 : sc1;
                const float bev = nf == 0 ? be0 : be1v;
#pragma unroll
                for (int rg = 0; rg < 4; ++rg) {
                    const int row = wr * 64 + rb * 16 + (lq << 2) + rg;
                    float v = fmaxf((acc1[rb][nf][rg] + b1c) * scv + bev, 0.f);
                    a1t[row * H + (col ^ ((row & 7) << 3))] = f2bf(v);
                }
            }
        __syncthreads();  // B: a1t ready

        // ---- GEMM2: a1t @ W2, C chained in acc2 ----
#pragma unroll
        for (int kc = 0; kc < 4; ++kc) {
            const int kb = kc * 32 + (lq << 3);
            short8 af[4], wf[2];
#pragma unroll
            for (int rb = 0; rb < 4; ++rb) {
                const int row = wr * 64 + rb * 16 + l15;
                af[rb] = *(const short8*)&a1t[row * H + (kb ^ ((row & 7) << 3))];
            }
#pragma unroll
            for (int nf = 0; nf < 2; ++nf)
                wf[nf] = *(const short8*)&wp[16384 + (c0 + nf * 16) * H + kb];
#pragma unroll
            for (int rb = 0; rb < 4; ++rb)
#pragma unroll
                for (int nf = 0; nf < 2; ++nf)
                    acc2[rb][nf] = __builtin_amdgcn_mfma_f32_16x16x32_bf16(
                        af[rb], wf[nf], acc2[rb][nf], 0, 0, 0);
        }
    }

    // ---- final epilogue: hnew = elu(acc2 + sum(b2) + hb) ----
    if (fin) {
        float* foutp = fout + (size_t)M.noffH[t];
#pragma unroll
        for (int rb = 0; rb < 4; ++rb)
#pragma unroll
            for (int nf = 0; nf < 2; ++nf) {
                const int col = c0 + nf * 16;
                const float b2s = nf == 0 ? b2s0 : b2s1;
#pragma unroll
                for (int rg = 0; rg < 4; ++rg) {
                    const int row = wr * 64 + rb * 16 + (lq << 2) + rg;
                    if (row < rows) {
                        const size_t o = (size_t)(r0 + row) * H + col;
                        foutp[o] = eluf(acc2[rb][nf][rg] + b2s
                                        + bf2f((unsigned int)hbp[o]));
                    }
                }
            }
    } else {
        unsigned short* hbwp = hbw + (size_t)M.noffH[t];
        __syncthreads();  // all GEMM2 reads of a1t done
#pragma unroll
        for (int rb = 0; rb < 4; ++rb)
#pragma unroll
            for (int nf = 0; nf < 2; ++nf) {
                const int col = c0 + nf * 16;
                const float b2s = nf == 0 ? b2s0 : b2s1;
#pragma unroll
                for (int rg = 0; rg < 4; ++rg) {
                    const int row = wr * 64 + rb * 16 + (lq << 2) + rg;
                    if (row < rows) {
                        const size_t o = (size_t)(r0 + row) * H + col;
                        a1t[row * H + col] = f2bf(eluf(acc2[rb][nf][rg] + b2s
                                                       + bf2f((unsigned int)hbp[o])));
                    }
                }
            }
        __syncthreads();
        uint2* d = (uint2*)&hbwp[(size_t)r0 * H];
        const uint2* s2 = (const uint2*)a1t;
        for (int idx = tid; idx < rows * 32; idx += 512) d[idx] = s2[idx];
    }
}

static inline int imin(int a, int b) { return a < b ? a : b; }
static inline size_t alignup(size_t x) { return (x + 255) & ~(size_t)255; }

extern "C" void kernel_launch(void* const* d_in, const int* in_sizes, int n_in,
                              void* d_out, int out_size, void* d_ws, size_t ws_size,
                              hipStream_t stream) {
    const float* xin[3] = {(const float*)d_in[0], (const float*)d_in[1], (const float*)d_in[2]};
    const int* src[7]; const int* dst[7]; const float* ea[7]; int E[7];
    for (int r = 0; r < 7; ++r) {
        src[r] = (const int*)d_in[3 + 3 * r];
        dst[r] = (const int*)d_in[4 + 3 * r];
        ea[r]  = (const float*)d_in[5 + 3 * r];
        E[r]   = in_sizes[3 + 3 * r];
    }
    const float* linW[3] = {(const float*)d_in[24], (const float*)d_in[26], (const float*)d_in[28]};
    const float* linb[3] = {(const float*)d_in[25], (const float*)d_in[27], (const float*)d_in[29]};
    const float* eW  = (const float*)d_in[30];
    const float* ebp = (const float*)d_in[31];
    const float* W1  = (const float*)d_in[32];
    const float* b1  = (const float*)d_in[33];
    const float* g1  = (const float*)d_in[34];
    const float* be1 = (const float*)d_in[35];
    const float* W2  = (const float*)d_in[36];
    const float* b2  = (const float*)d_in[37];

    const int NSn[3]  = {in_sizes[0] / 64, in_sizes[1] / 64, in_sizes[2] / 64};
    const int NTOT = NSn[0] + NSn[1] + NSn[2];
    const int noff[3] = {0, NSn[0], NSn[0] + NSn[1]};

    float* fout = (float*)d_out;

    // prefixes
    int eOff[8]; eOff[0] = 0;
    for (int r = 0; r < 7; ++r) eOff[r + 1] = eOff[r] + E[r];
    const int Etot = eOff[7];
    int bOff[8]; bOff[0] = 0;
    for (int r = 0; r < 7; ++r) bOff[r + 1] = bOff[r] + (NSn[DST_T_[r]] + 255) / 256;
    int nOff[8]; nOff[0] = 0;
    for (int r = 0; r < 7; ++r) nOff[r + 1] = nOff[r] + NSn[DST_T_[r]];

    // workspace carve-up
    char* wsb = (char*)d_ws;
    size_t off = 0;
    unsigned short* hb = (unsigned short*)(wsb + off); off = alignup(off + (size_t)NTOT * H * 2);
    unsigned short* zb[7];
    for (int r = 0; r < 7; ++r) {
        int nd = NSn[DST_T_[r]];
        zb[r] = (unsigned short*)(wsb + off); off = alignup(off + (size_t)nd * H * 2);
    }
    unsigned short* wprep = (unsigned short*)(wsb + off); off = alignup(off + (size_t)21 * 32768 * 2);
    int* deg    = (int*)(wsb + off); off = alignup(off + (size_t)bOff[7] * 256 * 4);
    int* cursor = (int*)(wsb + off); off = alignup(off + (size_t)bOff[7] * 256 * 4);
    int* bsum   = (int*)(wsb + off); off = alignup(off + (size_t)bOff[7] * 4 + 256);
    int* ptrs[7]; int* csrs[7]; uint2* ceas[7];
    for (int r = 0; r < 7; ++r) {
        int nd = NSn[DST_T_[r]];
        ptrs[r] = (int*)(wsb + off); off = alignup(off + (size_t)(nd + 1) * 4);
    }
    for (int r = 0; r < 7; ++r) {
        csrs[r] = (int*)(wsb + off); off = alignup(off + (size_t)E[r] * 4);
    }
    for (int r = 0; r < 7; ++r) {
        ceas[r] = (uint2*)(wsb + off); off = alignup(off + (size_t)E[r] * 8);
    }

    // ---- batched CSR build ----
    CsrCtx C;
    for (int r = 0; r < 7; ++r) {
        C.src[r] = src[r]; C.dst[r] = dst[r]; C.ea[r] = ea[r];
        C.csr_src[r] = csrs[r]; C.csr_ea[r] = ceas[r]; C.ptr[r] = ptrs[r];
        C.nd[r] = NSn[DST_T_[r]];
    }
    C.deg = deg; C.cursor = cursor; C.bsum = bsum;
    for (int r = 0; r < 8; ++r) { C.eOff[r] = eOff[r]; C.bOff[r] = bOff[r]; }

    hipMemsetAsync(deg, 0, (size_t)bOff[7] * 256 * 4, stream);
    k_hist_all<<<imin((Etot + 255) / 256, 8192), 256, 0, stream>>>(C, Etot);
    k_scan_partial_all<<<bOff[7], 256, 0, stream>>>(C);
    k_scan_mid_all<<<7, 512, 0, stream>>>(C);
    k_scan_final_all<<<bOff[7], 256, 0, stream>>>(C);
    k_scatter_all<<<imin((Etot + 255) / 256, 8192), 256, 0, stream>>>(C, Etot);
    k_wprep<<<1344, 256, 0, stream>>>(W1, W2, wprep, 21 * 16384);

    // ---- input embeddings (bf16 h) ----
    for (int t = 0; t < 3; ++t) {
        int n = NSn[t];
        k_input_linear<<<imin((n + 15) / 16, 2048), 128, 0, stream>>>(
            xin[t], linW[t], linb[t], hb + (size_t)noff[t] * H, n);
    }

    // ---- agg context ----
    AggCtx A;
    for (int r = 0; r < 7; ++r) {
        A.ptr[r] = ptrs[r]; A.csr_src[r] = csrs[r]; A.csr_ea[r] = ceas[r];
        A.hsrc[r] = hb + (size_t)noff[SRC_T_[r]] * H;
        A.hdst[r] = hb + (size_t)noff[DST_T_[r]] * H;
        A.z[r] = zb[r];
    }
    for (int r = 0; r < 8; ++r) A.nOff[r] = nOff[r];

    // ---- mlp context (per-type relation lists) ----
    static const int RELS[3][3] = {{0, 2, 0}, {1, 3, 5}, {4, 6, 0}};
    static const int NRELS[3] = {2, 3, 2};
    MlpCtx M;
    int gend = 0;
    for (int t = 0; t < 3; ++t) {
        M.nrel[t] = NRELS[t];
        M.noffH[t] = noff[t] * H;
        M.n[t] = NSn[t];
        gend += (NSn[t] + 127) / 128;
        M.gend[t] = gend;
        for (int k = 0; k < 3; ++k) M.z[t][k] = zb[RELS[t][k]];
    }

    // ---- layers ----
    for (int l = 0; l < 3; ++l) {
        const int fin = (l == 2) ? 1 : 0;
        k_aggz_all<<<(nOff[7] + 3) / 4, 256, 0, stream>>>(A, eW, ebp, l, nOff[7]);
        for (int t = 0; t < 3; ++t)
            for (int k = 0; k < 3; ++k) M.lr[t][k] = l * 7 + RELS[t][k];
        k_mlp_all<<<M.gend[2], 512, 0, stream>>>(
            M, hb, hb, fout, wprep, b1, g1, be1, b2, fin);
    }
}

// Round 9
// 913.158 us; speedup vs baseline: 1.9590x; 1.3266x over previous
//
#include <hip/hip_runtime.h>
#include <math.h>

#define H 128

typedef __attribute__((ext_vector_type(8))) short short8;
typedef __attribute__((ext_vector_type(4))) float f32x4;

static const int SRC_T_[7] = {0, 0, 1, 1, 1, 2, 2};
static const int DST_T_[7] = {0, 1, 0, 1, 2, 1, 2};

__device__ __forceinline__ float eluf(float x) {
    return x > 0.f ? x : (__expf(x) - 1.f);
}
__device__ __forceinline__ unsigned short f2bf(float x) {  // RNE f32->bf16
    union { float f; unsigned int u; } v; v.f = x;
    unsigned int r = v.u + 0x7fffu + ((v.u >> 16) & 1u);
    return (unsigned short)(r >> 16);
}
__device__ __forceinline__ float bf2f(unsigned int u) {
    union { unsigned int u; float f; } v; v.u = u << 16;
    return v.f;
}

// ---------------------------------------------------------------------------
// hb[t] = bf16(elu(x @ W + b)); x:[n,64], W:[64,128]
__global__ __launch_bounds__(128) void k_input_linear(
    const float* __restrict__ x, const float* __restrict__ W,
    const float* __restrict__ b, unsigned short* __restrict__ hb, int n)
{
    __shared__ float Ws[64 * H];
    __shared__ float xs[16 * 64];
    __shared__ unsigned short os[16 * H];
    const int j = threadIdx.x;
    for (int i = j; i < 64 * H; i += 128) Ws[i] = W[i];
    const float bj = b[j];

    for (int r0 = blockIdx.x * 16; r0 < n; r0 += gridDim.x * 16) {
        const int nrows = min(16, n - r0);
        __syncthreads();
        for (int i = j; i < nrows * 64; i += 128) xs[i] = x[(size_t)r0 * 64 + i];
        __syncthreads();
        for (int i = 0; i < nrows; ++i) {
            float acc = bj;
#pragma unroll
            for (int k = 0; k < 64; k += 4) {
                float4 xv = *(const float4*)&xs[i * 64 + k];
                acc += xv.x * Ws[(k + 0) * H + j] + xv.y * Ws[(k + 1) * H + j]
                     + xv.z * Ws[(k + 2) * H + j] + xv.w * Ws[(k + 3) * H + j];
            }
            os[i * H + j] = f2bf(eluf(acc));
        }
        __syncthreads();
        uint2* d = (uint2*)&hb[(size_t)r0 * H];
        const uint2* s2 = (const uint2*)os;
        for (int i = j; i < nrows * 32; i += 128) d[i] = s2[i];
    }
}

// --------------------------- batched CSR build ------------------------------
struct CsrCtx {
    const int* src[7]; const int* dst[7]; const float* ea[7];
    int* csr_src[7]; uint2* csr_ea[7]; int* ptr[7];
    int* deg; int* cursor; int* bsum;
    int eOff[8];
    int bOff[8];
    int nd[7];
};

__global__ __launch_bounds__(256) void k_hist_all(CsrCtx C, int Etot)
{
    for (int e = blockIdx.x * 256 + threadIdx.x; e < Etot; e += gridDim.x * 256) {
        int r = 0;
        while (e >= C.eOff[r + 1]) ++r;
        const int le = e - C.eOff[r];
        atomicAdd(&C.deg[(C.bOff[r] << 8) + C.dst[r][le]], 1);
    }
}

__global__ __launch_bounds__(256) void k_scan_partial_all(CsrCtx C)
{
    __shared__ int s[256];
    const int b = blockIdx.x;
    int r = 0;
    while (b >= C.bOff[r + 1]) ++r;
    const int lb = b - C.bOff[r];
    const int tid = threadIdx.x;
    const int idx = lb * 256 + tid;
    s[tid] = idx < C.nd[r] ? C.deg[(C.bOff[r] << 8) + idx] : 0;
    __syncthreads();
    for (int off = 128; off > 0; off >>= 1) {
        if (tid < off) s[tid] += s[tid + off];
        __syncthreads();
    }
    if (tid == 0) C.bsum[b] = s[0];
}

__global__ __launch_bounds__(512) void k_scan_mid_all(CsrCtx C)
{
    __shared__ int s[512];
    const int r = blockIdx.x;
    const int nb = C.bOff[r + 1] - C.bOff[r];
    const int tid = threadIdx.x;
    const int v = tid < nb ? C.bsum[C.bOff[r] + tid] : 0;
    s[tid] = v;
    __syncthreads();
    for (int off = 1; off < 512; off <<= 1) {
        int t = (tid >= off) ? s[tid - off] : 0;
        __syncthreads();
        s[tid] += t;
        __syncthreads();
    }
    if (tid < nb) C.bsum[C.bOff[r] + tid] = s[tid] - v;
    if (tid == nb - 1) C.ptr[r][C.nd[r]] = s[tid];
}

__global__ __launch_bounds__(256) void k_scan_final_all(CsrCtx C)
{
    __shared__ int s[256];
    const int b = blockIdx.x;
    int r = 0;
    while (b >= C.bOff[r + 1]) ++r;
    const int lb = b - C.bOff[r];
    const int tid = threadIdx.x;
    const int idx = lb * 256 + tid;
    const int v = idx < C.nd[r] ? C.deg[(C.bOff[r] << 8) + idx] : 0;
    s[tid] = v;
    __syncthreads();
    for (int off = 1; off < 256; off <<= 1) {
        int t = (tid >= off) ? s[tid - off] : 0;
        __syncthreads();
        s[tid] += t;
        __syncthreads();
    }
    if (idx < C.nd[r]) {
        const int excl = s[tid] - v + C.bsum[b];
        C.ptr[r][idx] = excl;
        C.cursor[(C.bOff[r] << 8) + idx] = excl;
    }
}

__global__ __launch_bounds__(256) void k_scatter_all(CsrCtx C, int Etot)
{
    for (int e = blockIdx.x * 256 + threadIdx.x; e < Etot; e += gridDim.x * 256) {
        int r = 0;
        while (e >= C.eOff[r + 1]) ++r;
        const int le = e - C.eOff[r];
        const int d = C.dst[r][le];
        const int pos = atomicAdd(&C.cursor[(C.bOff[r] << 8) + d], 1);
        C.csr_src[r][pos] = C.src[r][le];
        const float* eap = C.ea[r] + (size_t)3 * le;
        uint2 p;
        p.x = (unsigned int)f2bf(eap[0]) | ((unsigned int)f2bf(eap[1]) << 16);
        p.y = (unsigned int)f2bf(eap[2]);
        C.csr_ea[r][pos] = p;
    }
}

// ---------------------------------------------------------------------------
// Weight prep: W1,W2 [21][128k][128c] f32 -> wp [21][2][128c][128k] bf16
__global__ __launch_bounds__(256) void k_wprep(
    const float* __restrict__ W1, const float* __restrict__ W2,
    unsigned short* __restrict__ wp, int total)
{
    for (int i = blockIdx.x * 256 + threadIdx.x; i < total; i += gridDim.x * 256) {
        int lr = i >> 14, rem = i & 16383;
        int c = rem >> 7, k = rem & 127;
        wp[(size_t)(lr * 2 + 0) * 16384 + rem] = f2bf(W1[(size_t)lr * 16384 + k * H + c]);
        wp[(size_t)(lr * 2 + 1) * 16384 + rem] = f2bf(W2[(size_t)lr * 16384 + k * H + c]);
    }
}

// ---------------------------------------------------------------------------
// Batched gather-aggregate v4: per-relation block ranges; 4 waves/block;
// each wave = 16 consecutive nodes serially, full wave per node (2 cols/lane),
// weights hoisted per block, ptr chained, hdst folded into acc init.
//   z_r[d] = bf16( hb_dst[d] + sum_e relu(hb_src + ea@eW + eb) )
struct AggCtx {
    const int* ptr[7]; const int* csr_src[7]; const uint2* csr_ea[7];
    const unsigned short* hsrc[7]; const unsigned short* hdst[7];
    unsigned short* z[7];
    int gOff[8];   // block-range prefix per relation (64 nodes per block)
    int nd[7];
};

__global__ __launch_bounds__(256) void k_aggz_all(
    AggCtx A, const float* __restrict__ eW, const float* __restrict__ eb, int l)
{
    const int b = blockIdx.x;
    int r = 0;
    while (b >= A.gOff[r + 1]) ++r;
    const int lb = b - A.gOff[r];
    const int wave = threadIdx.x >> 6;
    const int lane = threadIdx.x & 63;
    const int t2 = lane << 1;
    const int lr = l * 7 + r;
    const float* eWr = eW + (size_t)lr * 3 * H;
    const float* ebr = eb + (size_t)lr * H;
    const float w00 = eWr[t2],         w01 = eWr[t2 + 1];
    const float w10 = eWr[H + t2],     w11 = eWr[H + t2 + 1];
    const float w20 = eWr[2 * H + t2], w21 = eWr[2 * H + t2 + 1];
    const float b0 = ebr[t2], b1v = ebr[t2 + 1];

    const int nd = A.nd[r];
    const int d0 = lb * 64 + wave * 16;
    if (d0 >= nd) return;
    const int dend = min(d0 + 16, nd);
    const int* __restrict__ ptr = A.ptr[r];
    const int* __restrict__ cs = A.csr_src[r];
    const uint2* __restrict__ ce = A.csr_ea[r];
    const unsigned short* __restrict__ hs = A.hsrc[r];
    const unsigned short* __restrict__ hd = A.hdst[r];
    unsigned int* __restrict__ zp = (unsigned int*)A.z[r];

    int p1 = ptr[d0];
    for (int d = d0; d < dend; ++d) {
        const int p0 = p1;
        p1 = ptr[d + 1];
        const unsigned int hdv = ((const unsigned int*)&hd[(size_t)d * H])[lane];
        float acc0 = bf2f(hdv & 0xffffu);
        float acc1 = bf2f(hdv >> 16);
        int i = p0;
        for (; i + 1 < p1; i += 2) {
            const int s0 = cs[i], s1 = cs[i + 1];
            const uint2 e0 = ce[i], e1 = ce[i + 1];
            const unsigned int hv0 = ((const unsigned int*)&hs[(size_t)s0 * H])[lane];
            const unsigned int hv1 = ((const unsigned int*)&hs[(size_t)s1 * H])[lane];
            const float a00 = bf2f(e0.x & 0xffffu), a01 = bf2f(e0.x >> 16), a02 = bf2f(e0.y & 0xffffu);
            const float a10 = bf2f(e1.x & 0xffffu), a11 = bf2f(e1.x >> 16), a12 = bf2f(e1.y & 0xffffu);
            acc0 += fmaxf(bf2f(hv0 & 0xffffu) + a00 * w00 + a01 * w10 + a02 * w20 + b0, 0.f)
                  + fmaxf(bf2f(hv1 & 0xffffu) + a10 * w00 + a11 * w10 + a12 * w20 + b0, 0.f);
            acc1 += fmaxf(bf2f(hv0 >> 16) + a00 * w01 + a01 * w11 + a02 * w21 + b1v, 0.f)
                  + fmaxf(bf2f(hv1 >> 16) + a10 * w01 + a11 * w11 + a12 * w21 + b1v, 0.f);
        }
        if (i < p1) {
            const int s = cs[i];
            const uint2 ep = ce[i];
            const float a0 = bf2f(ep.x & 0xffffu);
            const float a1 = bf2f(ep.x >> 16);
            const float a2 = bf2f(ep.y & 0xffffu);
            const unsigned int hv = ((const unsigned int*)&hs[(size_t)s * H])[lane];
            acc0 += fmaxf(bf2f(hv & 0xffffu) + a0 * w00 + a1 * w10 + a2 * w20 + b0, 0.f);
            acc1 += fmaxf(bf2f(hv >> 16)     + a0 * w01 + a1 * w11 + a2 * w21 + b1v, 0.f);
        }
        zp[(size_t)d * 64 + lane] =
            (unsigned int)f2bf(acc0) | ((unsigned int)f2bf(acc1) << 16);
    }
}

// ---------------------------------------------------------------------------
// One dispatch per layer: all 3 dst-types' fused MLPs.
//   hnew = elu( sum_rel (relu(z_rel@W1*bn+..)@W2 + b2) + hb )
struct MlpCtx {
    const unsigned short* z[3][3];
    int lr[3][3];
    int nrel[3];
    int gend[3];     // cumulative block-range ends per type
    int noffH[3];    // node offset * H
    int n[3];
};

__global__ __launch_bounds__(512, 4) void k_mlp_all(
    MlpCtx M, const unsigned short* __restrict__ hb,
    unsigned short* __restrict__ hbw, float* __restrict__ fout,
    const unsigned short* __restrict__ wprep,
    const float* __restrict__ b1g, const float* __restrict__ g1g,
    const float* __restrict__ be1g, const float* __restrict__ b2g, int fin)
{
    __shared__ unsigned short zt[128 * H];   // 32 KB, XOR-swizzled
    __shared__ unsigned short a1t[128 * H];  // 32 KB, XOR-swizzled

    const int b = blockIdx.x;
    const int t = (b >= M.gend[0] ? 1 : 0) + (b >= M.gend[1] ? 1 : 0);
    const int lb = b - (t == 0 ? 0 : M.gend[t - 1]);
    const int n = M.n[t];
    const int nrel = M.nrel[t];
    const unsigned short* hbp = hb + (size_t)M.noffH[t];

    const int tid = threadIdx.x;
    const int lane = tid & 63;
    const int wave = tid >> 6;
    const int wr = wave >> 2;
    const int wc = wave & 3;
    const int l15 = lane & 15;
    const int lq  = lane >> 4;
    const int c0 = wc * 32 + l15;

    const int r0 = lb * 128;
    const int rows = min(128, n - r0);

    const float bn_inv = 0.99999500003749977f;
    const f32x4 Z4 = {0.f, 0.f, 0.f, 0.f};
    f32x4 acc2[4][2];
#pragma unroll
    for (int rb = 0; rb < 4; ++rb)
#pragma unroll
        for (int nf = 0; nf < 2; ++nf) acc2[rb][nf] = Z4;
    float b2s0 = 0.f, b2s1 = 0.f;

    for (int rl = 0; rl < nrel; ++rl) {
        const unsigned short* z = M.z[t][rl];
        const int lr = M.lr[t][rl];
        const unsigned short* wp = wprep + (size_t)lr * 32768;
        const float b1c0 = b1g[lr * H + c0],            b1c1 = b1g[lr * H + c0 + 16];
        const float sc0  = g1g[lr * H + c0] * bn_inv,   sc1  = g1g[lr * H + c0 + 16] * bn_inv;
        const float be0  = be1g[lr * H + c0],           be1v = be1g[lr * H + c0 + 16];
        b2s0 += b2g[lr * H + c0]; b2s1 += b2g[lr * H + c0 + 16];

        // ---- stage z tile -> zt (swizzled) ----
        if (rows == 128) {
            uint4 v[4];
#pragma unroll
            for (int it = 0; it < 4; ++it) {
                const int idx = tid + it * 512;
                const int row = idx >> 4, cg = (idx & 15) << 3;
                v[it] = *(const uint4*)&z[(size_t)(r0 + row) * H + cg];
            }
#pragma unroll
            for (int it = 0; it < 4; ++it) {
                const int idx = tid + it * 512;
                const int row = idx >> 4, cg = (idx & 15) << 3;
                *(uint4*)&zt[row * H + (cg ^ ((row & 7) << 3))] = v[it];
            }
        } else {
            for (int idx = tid; idx < rows * 16; idx += 512) {
                const int row = idx >> 4, cg = (idx & 15) << 3;
                uint4 v = *(const uint4*)&z[(size_t)(r0 + row) * H + cg];
                *(uint4*)&zt[row * H + (cg ^ ((row & 7) << 3))] = v;
            }
        }
        __syncthreads();  // A: zt ready

        // ---- GEMM1: zt @ W1 ----
        f32x4 acc1[4][2];
#pragma unroll
        for (int rb = 0; rb < 4; ++rb)
#pragma unroll
            for (int nf = 0; nf < 2; ++nf) acc1[rb][nf] = Z4;
#pragma unroll
        for (int kc = 0; kc < 4; ++kc) {
            const int kb = kc * 32 + (lq << 3);
            short8 af[4], wf[2];
#pragma unroll
            for (int rb = 0; rb < 4; ++rb) {
                const int row = wr * 64 + rb * 16 + l15;
                af[rb] = *(const short8*)&zt[row * H + (kb ^ ((row & 7) << 3))];
            }
#pragma unroll
            for (int nf = 0; nf < 2; ++nf)
                wf[nf] = *(const short8*)&wp[(c0 + nf * 16) * H + kb];
#pragma unroll
            for (int rb = 0; rb < 4; ++rb)
#pragma unroll
                for (int nf = 0; nf < 2; ++nf)
                    acc1[rb][nf] = __builtin_amdgcn_mfma_f32_16x16x32_bf16(
                        af[rb], wf[nf], acc1[rb][nf], 0, 0, 0);
        }
        // epilogue1: BN+ReLU -> a1t (swizzled)
#pragma unroll
        for (int rb = 0; rb < 4; ++rb)
#pragma unroll
            for (int nf = 0; nf < 2; ++nf) {
                const int col = c0 + nf * 16;
                const float b1c = nf == 0 ? b1c0 : b1c1;
                const float scv = nf == 0 ? sc0 : sc1;
                const float bev = nf == 0 ? be0 : be1v;
#pragma unroll
                for (int rg = 0; rg < 4; ++rg) {
                    const int row = wr * 64 + rb * 16 + (lq << 2) + rg;
                    float v = fmaxf((acc1[rb][nf][rg] + b1c) * scv + bev, 0.f);
                    a1t[row * H + (col ^ ((row & 7) << 3))] = f2bf(v);
                }
            }
        __syncthreads();  // B: a1t ready

        // ---- GEMM2: a1t @ W2, C chained in acc2 ----
#pragma unroll
        for (int kc = 0; kc < 4; ++kc) {
            const int kb = kc * 32 + (lq << 3);
            short8 af[4], wf[2];
#pragma unroll
            for (int rb = 0; rb < 4; ++rb) {
                const int row = wr * 64 + rb * 16 + l15;
                af[rb] = *(const short8*)&a1t[row * H + (kb ^ ((row & 7) << 3))];
            }
#pragma unroll
            for (int nf = 0; nf < 2; ++nf)
                wf[nf] = *(const short8*)&wp[16384 + (c0 + nf * 16) * H + kb];
#pragma unroll
            for (int rb = 0; rb < 4; ++rb)
#pragma unroll
                for (int nf = 0; nf < 2; ++nf)
                    acc2[rb][nf] = __builtin_amdgcn_mfma_f32_16x16x32_bf16(
                        af[rb], wf[nf], acc2[rb][nf], 0, 0, 0);
        }
    }

    // ---- final epilogue: hnew = elu(acc2 + sum(b2) + hb) ----
    if (fin) {
        float* foutp = fout + (size_t)M.noffH[t];
#pragma unroll
        for (int rb = 0; rb < 4; ++rb)
#pragma unroll
            for (int nf = 0; nf < 2; ++nf) {
                const int col = c0 + nf * 16;
                const float b2s = nf == 0 ? b2s0 : b2s1;
#pragma unroll
                for (int rg = 0; rg < 4; ++rg) {
                    const int row = wr * 64 + rb * 16 + (lq << 2) + rg;
                    if (row < rows) {
                        const size_t o = (size_t)(r0 + row) * H + col;
                        foutp[o] = eluf(acc2[rb][nf][rg] + b2s
                                        + bf2f((unsigned int)hbp[o]));
                    }
                }
            }
    } else {
        unsigned short* hbwp = hbw + (size_t)M.noffH[t];
        __syncthreads();  // all GEMM2 reads of a1t done
#pragma unroll
        for (int rb = 0; rb < 4; ++rb)
#pragma unroll
            for (int nf = 0; nf < 2; ++nf) {
                const int col = c0 + nf * 16;
                const float b2s = nf == 0 ? b2s0 : b2s1;
#pragma unroll
                for (int rg = 0; rg < 4; ++rg) {
                    const int row = wr * 64 + rb * 16 + (lq << 2) + rg;
                    if (row < rows) {
                        const size_t o = (size_t)(r0 + row) * H + col;
                        a1t[row * H + col] = f2bf(eluf(acc2[rb][nf][rg] + b2s
                                                       + bf2f((unsigned int)hbp[o])));
                    }
                }
            }
        __syncthreads();
        uint2* d = (uint2*)&hbwp[(size_t)r0 * H];
        const uint2* s2 = (const uint2*)a1t;
        for (int idx = tid; idx < rows * 32; idx += 512) d[idx] = s2[idx];
    }
}

static inline int imin(int a, int b) { return a < b ? a : b; }
static inline size_t alignup(size_t x) { return (x + 255) & ~(size_t)255; }

extern "C" void kernel_launch(void* const* d_in, const int* in_sizes, int n_in,
                              void* d_out, int out_size, void* d_ws, size_t ws_size,
                              hipStream_t stream) {
    const float* xin[3] = {(const float*)d_in[0], (const float*)d_in[1], (const float*)d_in[2]};
    const int* src[7]; const int* dst[7]; const float* ea[7]; int E[7];
    for (int r = 0; r < 7; ++r) {
        src[r] = (const int*)d_in[3 + 3 * r];
        dst[r] = (const int*)d_in[4 + 3 * r];
        ea[r]  = (const float*)d_in[5 + 3 * r];
        E[r]   = in_sizes[3 + 3 * r];
    }
    const float* linW[3] = {(const float*)d_in[24], (const float*)d_in[26], (const float*)d_in[28]};
    const float* linb[3] = {(const float*)d_in[25], (const float*)d_in[27], (const float*)d_in[29]};
    const float* eW  = (const float*)d_in[30];
    const float* ebp = (const float*)d_in[31];
    const float* W1  = (const float*)d_in[32];
    const float* b1  = (const float*)d_in[33];
    const float* g1  = (const float*)d_in[34];
    const float* be1 = (const float*)d_in[35];
    const float* W2  = (const float*)d_in[36];
    const float* b2  = (const float*)d_in[37];

    const int NSn[3]  = {in_sizes[0] / 64, in_sizes[1] / 64, in_sizes[2] / 64};
    const int NTOT = NSn[0] + NSn[1] + NSn[2];
    const int noff[3] = {0, NSn[0], NSn[0] + NSn[1]};

    float* fout = (float*)d_out;

    // prefixes
    int eOff[8]; eOff[0] = 0;
    for (int r = 0; r < 7; ++r) eOff[r + 1] = eOff[r] + E[r];
    const int Etot = eOff[7];
    int bOff[8]; bOff[0] = 0;
    for (int r = 0; r < 7; ++r) bOff[r + 1] = bOff[r] + (NSn[DST_T_[r]] + 255) / 256;
    int gOff[8]; gOff[0] = 0;
    for (int r = 0; r < 7; ++r) gOff[r + 1] = gOff[r] + (NSn[DST_T_[r]] + 63) / 64;

    // workspace carve-up
    char* wsb = (char*)d_ws;
    size_t off = 0;
    unsigned short* hb = (unsigned short*)(wsb + off); off = alignup(off + (size_t)NTOT * H * 2);
    unsigned short* zb[7];
    for (int r = 0; r < 7; ++r) {
        int nd = NSn[DST_T_[r]];
        zb[r] = (unsigned short*)(wsb + off); off = alignup(off + (size_t)nd * H * 2);
    }
    unsigned short* wprep = (unsigned short*)(wsb + off); off = alignup(off + (size_t)21 * 32768 * 2);
    int* deg    = (int*)(wsb + off); off = alignup(off + (size_t)bOff[7] * 256 * 4);
    int* cursor = (int*)(wsb + off); off = alignup(off + (size_t)bOff[7] * 256 * 4);
    int* bsum   = (int*)(wsb + off); off = alignup(off + (size_t)bOff[7] * 4 + 256);
    int* ptrs[7]; int* csrs[7]; uint2* ceas[7];
    for (int r = 0; r < 7; ++r) {
        int nd = NSn[DST_T_[r]];
        ptrs[r] = (int*)(wsb + off); off = alignup(off + (size_t)(nd + 1) * 4);
    }
    for (int r = 0; r < 7; ++r) {
        csrs[r] = (int*)(wsb + off); off = alignup(off + (size_t)E[r] * 4);
    }
    for (int r = 0; r < 7; ++r) {
        ceas[r] = (uint2*)(wsb + off); off = alignup(off + (size_t)E[r] * 8);
    }

    // ---- batched CSR build ----
    CsrCtx C;
    for (int r = 0; r < 7; ++r) {
        C.src[r] = src[r]; C.dst[r] = dst[r]; C.ea[r] = ea[r];
        C.csr_src[r] = csrs[r]; C.csr_ea[r] = ceas[r]; C.ptr[r] = ptrs[r];
        C.nd[r] = NSn[DST_T_[r]];
    }
    C.deg = deg; C.cursor = cursor; C.bsum = bsum;
    for (int r = 0; r < 8; ++r) { C.eOff[r] = eOff[r]; C.bOff[r] = bOff[r]; }

    hipMemsetAsync(deg, 0, (size_t)bOff[7] * 256 * 4, stream);
    k_hist_all<<<imin((Etot + 255) / 256, 8192), 256, 0, stream>>>(C, Etot);
    k_scan_partial_all<<<bOff[7], 256, 0, stream>>>(C);
    k_scan_mid_all<<<7, 512, 0, stream>>>(C);
    k_scan_final_all<<<bOff[7], 256, 0, stream>>>(C);
    k_scatter_all<<<imin((Etot + 255) / 256, 8192), 256, 0, stream>>>(C, Etot);
    k_wprep<<<1344, 256, 0, stream>>>(W1, W2, wprep, 21 * 16384);

    // ---- input embeddings (bf16 h) ----
    for (int t = 0; t < 3; ++t) {
        int n = NSn[t];
        k_input_linear<<<imin((n + 15) / 16, 2048), 128, 0, stream>>>(
            xin[t], linW[t], linb[t], hb + (size_t)noff[t] * H, n);
    }

    // ---- agg context ----
    AggCtx A;
    for (int r = 0; r < 7; ++r) {
        A.ptr[r] = ptrs[r]; A.csr_src[r] = csrs[r]; A.csr_ea[r] = ceas[r];
        A.hsrc[r] = hb + (size_t)noff[SRC_T_[r]] * H;
        A.hdst[r] = hb + (size_t)noff[DST_T_[r]] * H;
        A.z[r] = zb[r];
        A.nd[r] = NSn[DST_T_[r]];
    }
    for (int r = 0; r < 8; ++r) A.gOff[r] = gOff[r];

    // ---- mlp context (per-type relation lists) ----
    static const int RELS[3][3] = {{0, 2, 0}, {1, 3, 5}, {4, 6, 0}};
    static const int NRELS[3] = {2, 3, 2};
    MlpCtx M;
    int gend = 0;
    for (int t = 0; t < 3; ++t) {
        M.nrel[t] = NRELS[t];
        M.noffH[t] = noff[t] * H;
        M.n[t] = NSn[t];
        gend += (NSn[t] + 127) / 128;
        M.gend[t] = gend;
        for (int k = 0; k < 3; ++k) M.z[t][k] = zb[RELS[t][k]];
    }

    // ---- layers ----
    for (int l = 0; l < 3; ++l) {
        const int fin = (l == 2) ? 1 : 0;
        k_aggz_all<<<gOff[7], 256, 0, stream>>>(A, eW, ebp, l);
        for (int t = 0; t < 3; ++t)
            for (int k = 0; k < 3; ++k) M.lr[t][k] = l * 7 + RELS[t][k];
        k_mlp_all<<<M.gend[2], 512, 0, stream>>>(
            M, hb, hb, fout, wprep, b1, g1, be1, b2, fin);
    }
}

// Round 10
// 896.299 us; speedup vs baseline: 1.9959x; 1.0188x over previous
//
#include <hip/hip_runtime.h>
#include <math.h>

#define H 128

typedef __attribute__((ext_vector_type(8))) short short8;
typedef __attribute__((ext_vector_type(4))) float f32x4;

static const int SRC_T_[7] = {0, 0, 1, 1, 1, 2, 2};
static const int DST_T_[7] = {0, 1, 0, 1, 2, 1, 2};

__device__ __forceinline__ float eluf(float x) {
    return x > 0.f ? x : (__expf(x) - 1.f);
}
__device__ __forceinline__ unsigned short f2bf(float x) {  // RNE f32->bf16
    union { float f; unsigned int u; } v; v.f = x;
    unsigned int r = v.u + 0x7fffu + ((v.u >> 16) & 1u);
    return (unsigned short)(r >> 16);
}
__device__ __forceinline__ float bf2f(unsigned int u) {
    union { unsigned int u; float f; } v; v.u = u << 16;
    return v.f;
}

// async global->LDS, 16 bytes per lane; lds base wave-uniform, gsrc per-lane
#define GLDS16(gp, lp) __builtin_amdgcn_global_load_lds( \
    (const __attribute__((address_space(1))) void*)(gp), \
    (__attribute__((address_space(3))) void*)(lp), 16, 0, 0)

// ---------------------------------------------------------------------------
// hb[t] = bf16(elu(x @ W + b)); x:[n,64], W:[64,128]
__global__ __launch_bounds__(128) void k_input_linear(
    const float* __restrict__ x, const float* __restrict__ W,
    const float* __restrict__ b, unsigned short* __restrict__ hb, int n)
{
    __shared__ float Ws[64 * H];
    __shared__ float xs[16 * 64];
    __shared__ unsigned short os[16 * H];
    const int j = threadIdx.x;
    for (int i = j; i < 64 * H; i += 128) Ws[i] = W[i];
    const float bj = b[j];

    for (int r0 = blockIdx.x * 16; r0 < n; r0 += gridDim.x * 16) {
        const int nrows = min(16, n - r0);
        __syncthreads();
        for (int i = j; i < nrows * 64; i += 128) xs[i] = x[(size_t)r0 * 64 + i];
        __syncthreads();
        for (int i = 0; i < nrows; ++i) {
            float acc = bj;
#pragma unroll
            for (int k = 0; k < 64; k += 4) {
                float4 xv = *(const float4*)&xs[i * 64 + k];
                acc += xv.x * Ws[(k + 0) * H + j] + xv.y * Ws[(k + 1) * H + j]
                     + xv.z * Ws[(k + 2) * H + j] + xv.w * Ws[(k + 3) * H + j];
            }
            os[i * H + j] = f2bf(eluf(acc));
        }
        __syncthreads();
        uint2* d = (uint2*)&hb[(size_t)r0 * H];
        const uint2* s2 = (const uint2*)os;
        for (int i = j; i < nrows * 32; i += 128) d[i] = s2[i];
    }
}

// --------------------------- batched CSR build ------------------------------
struct CsrCtx {
    const int* src[7]; const int* dst[7]; const float* ea[7];
    int* csr_src[7]; uint2* csr_ea[7]; int* ptr[7];
    int* deg; int* cursor; int* bsum;
    int eOff[8];
    int bOff[8];
    int nd[7];
};

__global__ __launch_bounds__(256) void k_hist_all(CsrCtx C, int Etot)
{
    for (int e = blockIdx.x * 256 + threadIdx.x; e < Etot; e += gridDim.x * 256) {
        int r = 0;
        while (e >= C.eOff[r + 1]) ++r;
        const int le = e - C.eOff[r];
        atomicAdd(&C.deg[(C.bOff[r] << 8) + C.dst[r][le]], 1);
    }
}

__global__ __launch_bounds__(256) void k_scan_partial_all(CsrCtx C)
{
    __shared__ int s[256];
    const int b = blockIdx.x;
    int r = 0;
    while (b >= C.bOff[r + 1]) ++r;
    const int lb = b - C.bOff[r];
    const int tid = threadIdx.x;
    const int idx = lb * 256 + tid;
    s[tid] = idx < C.nd[r] ? C.deg[(C.bOff[r] << 8) + idx] : 0;
    __syncthreads();
    for (int off = 128; off > 0; off >>= 1) {
        if (tid < off) s[tid] += s[tid + off];
        __syncthreads();
    }
    if (tid == 0) C.bsum[b] = s[0];
}

__global__ __launch_bounds__(512) void k_scan_mid_all(CsrCtx C)
{
    __shared__ int s[512];
    const int r = blockIdx.x;
    const int nb = C.bOff[r + 1] - C.bOff[r];
    const int tid = threadIdx.x;
    const int v = tid < nb ? C.bsum[C.bOff[r] + tid] : 0;
    s[tid] = v;
    __syncthreads();
    for (int off = 1; off < 512; off <<= 1) {
        int t = (tid >= off) ? s[tid - off] : 0;
        __syncthreads();
        s[tid] += t;
        __syncthreads();
    }
    if (tid < nb) C.bsum[C.bOff[r] + tid] = s[tid] - v;
    if (tid == nb - 1) C.ptr[r][C.nd[r]] = s[tid];
}

__global__ __launch_bounds__(256) void k_scan_final_all(CsrCtx C)
{
    __shared__ int s[256];
    const int b = blockIdx.x;
    int r = 0;
    while (b >= C.bOff[r + 1]) ++r;
    const int lb = b - C.bOff[r];
    const int tid = threadIdx.x;
    const int idx = lb * 256 + tid;
    const int v = idx < C.nd[r] ? C.deg[(C.bOff[r] << 8) + idx] : 0;
    s[tid] = v;
    __syncthreads();
    for (int off = 1; off < 256; off <<= 1) {
        int t = (tid >= off) ? s[tid - off] : 0;
        __syncthreads();
        s[tid] += t;
        __syncthreads();
    }
    if (idx < C.nd[r]) {
        const int excl = s[tid] - v + C.bsum[b];
        C.ptr[r][idx] = excl;
        C.cursor[(C.bOff[r] << 8) + idx] = excl;
    }
}

__global__ __launch_bounds__(256) void k_scatter_all(CsrCtx C, int Etot)
{
    for (int e = blockIdx.x * 256 + threadIdx.x; e < Etot; e += gridDim.x * 256) {
        int r = 0;
        while (e >= C.eOff[r + 1]) ++r;
        const int le = e - C.eOff[r];
        const int d = C.dst[r][le];
        const int pos = atomicAdd(&C.cursor[(C.bOff[r] << 8) + d], 1);
        C.csr_src[r][pos] = C.src[r][le];
        const float* eap = C.ea[r] + (size_t)3 * le;
        uint2 p;
        p.x = (unsigned int)f2bf(eap[0]) | ((unsigned int)f2bf(eap[1]) << 16);
        p.y = (unsigned int)f2bf(eap[2]);
        C.csr_ea[r][pos] = p;
    }
}

// ---------------------------------------------------------------------------
// Weight prep: W1,W2 [21][128k][128c] f32 -> wp [21][2][128c][128k] bf16
__global__ __launch_bounds__(256) void k_wprep(
    const float* __restrict__ W1, const float* __restrict__ W2,
    unsigned short* __restrict__ wp, int total)
{
    for (int i = blockIdx.x * 256 + threadIdx.x; i < total; i += gridDim.x * 256) {
        int lr = i >> 14, rem = i & 16383;
        int c = rem >> 7, k = rem & 127;
        wp[(size_t)(lr * 2 + 0) * 16384 + rem] = f2bf(W1[(size_t)lr * 16384 + k * H + c]);
        wp[(size_t)(lr * 2 + 1) * 16384 + rem] = f2bf(W2[(size_t)lr * 16384 + k * H + c]);
    }
}

// ---------------------------------------------------------------------------
// Batched gather-aggregate: per-relation block ranges; 4 waves/block;
// wave = 16 consecutive nodes, full wave per node (2 cols/lane).
// z written PRE-SWIZZLED: uint index lane ^ ((d&7)<<2)  (st-swizzle for MLP LDS)
struct AggCtx {
    const int* ptr[7]; const int* csr_src[7]; const uint2* csr_ea[7];
    const unsigned short* hsrc[7]; const unsigned short* hdst[7];
    unsigned short* z[7];
    int gOff[8];
    int nd[7];
};

__global__ __launch_bounds__(256) void k_aggz_all(
    AggCtx A, const float* __restrict__ eW, const float* __restrict__ eb, int l)
{
    const int b = blockIdx.x;
    int r = 0;
    while (b >= A.gOff[r + 1]) ++r;
    const int lb = b - A.gOff[r];
    const int wave = threadIdx.x >> 6;
    const int lane = threadIdx.x & 63;
    const int t2 = lane << 1;
    const int lr = l * 7 + r;
    const float* eWr = eW + (size_t)lr * 3 * H;
    const float* ebr = eb + (size_t)lr * H;
    const float w00 = eWr[t2],         w01 = eWr[t2 + 1];
    const float w10 = eWr[H + t2],     w11 = eWr[H + t2 + 1];
    const float w20 = eWr[2 * H + t2], w21 = eWr[2 * H + t2 + 1];
    const float b0 = ebr[t2], b1v = ebr[t2 + 1];

    const int nd = A.nd[r];
    const int d0 = lb * 64 + wave * 16;
    if (d0 >= nd) return;
    const int dend = min(d0 + 16, nd);
    const int* __restrict__ ptr = A.ptr[r];
    const int* __restrict__ cs = A.csr_src[r];
    const uint2* __restrict__ ce = A.csr_ea[r];
    const unsigned short* __restrict__ hs = A.hsrc[r];
    const unsigned short* __restrict__ hd = A.hdst[r];
    unsigned int* __restrict__ zp = (unsigned int*)A.z[r];

    int p1 = ptr[d0];
    for (int d = d0; d < dend; ++d) {
        const int p0 = p1;
        p1 = ptr[d + 1];
        const unsigned int hdv = ((const unsigned int*)&hd[(size_t)d * H])[lane];
        float acc0 = bf2f(hdv & 0xffffu);
        float acc1 = bf2f(hdv >> 16);
        int i = p0;
        for (; i + 1 < p1; i += 2) {
            const int s0 = cs[i], s1 = cs[i + 1];
            const uint2 e0 = ce[i], e1 = ce[i + 1];
            const unsigned int hv0 = ((const unsigned int*)&hs[(size_t)s0 * H])[lane];
            const unsigned int hv1 = ((const unsigned int*)&hs[(size_t)s1 * H])[lane];
            const float a00 = bf2f(e0.x & 0xffffu), a01 = bf2f(e0.x >> 16), a02 = bf2f(e0.y & 0xffffu);
            const float a10 = bf2f(e1.x & 0xffffu), a11 = bf2f(e1.x >> 16), a12 = bf2f(e1.y & 0xffffu);
            acc0 += fmaxf(bf2f(hv0 & 0xffffu) + a00 * w00 + a01 * w10 + a02 * w20 + b0, 0.f)
                  + fmaxf(bf2f(hv1 & 0xffffu) + a10 * w00 + a11 * w10 + a12 * w20 + b0, 0.f);
            acc1 += fmaxf(bf2f(hv0 >> 16) + a00 * w01 + a01 * w11 + a02 * w21 + b1v, 0.f)
                  + fmaxf(bf2f(hv1 >> 16) + a10 * w01 + a11 * w11 + a12 * w21 + b1v, 0.f);
        }
        if (i < p1) {
            const int s = cs[i];
            const uint2 ep = ce[i];
            const float a0 = bf2f(ep.x & 0xffffu);
            const float a1 = bf2f(ep.x >> 16);
            const float a2 = bf2f(ep.y & 0xffffu);
            const unsigned int hv = ((const unsigned int*)&hs[(size_t)s * H])[lane];
            acc0 += fmaxf(bf2f(hv & 0xffffu) + a0 * w00 + a1 * w10 + a2 * w20 + b0, 0.f);
            acc1 += fmaxf(bf2f(hv >> 16)     + a0 * w01 + a1 * w11 + a2 * w21 + b1v, 0.f);
        }
        // pre-swizzled store (uint idx XOR (d&7)<<2  ==  bf16 idx XOR (d&7)<<3)
        zp[(size_t)d * 64 + (lane ^ ((d & 7) << 2))] =
            (unsigned int)f2bf(acc0) | ((unsigned int)f2bf(acc1) << 16);
    }
}

// ---------------------------------------------------------------------------
// One dispatch per layer: all 3 dst-types' fused MLPs.
// z is pre-swizzled in global; staged via global_load_lds (linear copy);
// next relation's staging issued after the a1t barrier (flies under GEMM2).
struct MlpCtx {
    const unsigned short* z[3][3];
    int lr[3][3];
    int nrel[3];
    int gend[3];
    int noffH[3];
    int n[3];
};

__global__ __launch_bounds__(512, 4) void k_mlp_all(
    MlpCtx M, const unsigned short* __restrict__ hb,
    unsigned short* __restrict__ hbw, float* __restrict__ fout,
    const unsigned short* __restrict__ wprep,
    const float* __restrict__ b1g, const float* __restrict__ g1g,
    const float* __restrict__ be1g, const float* __restrict__ b2g, int fin)
{
    __shared__ unsigned short zt[128 * H];   // 32 KB, holds pre-swizzled rows
    __shared__ unsigned short a1t[128 * H];  // 32 KB, XOR-swizzled

    const int b = blockIdx.x;
    const int t = (b >= M.gend[0] ? 1 : 0) + (b >= M.gend[1] ? 1 : 0);
    const int lb = b - (t == 0 ? 0 : M.gend[t - 1]);
    const int n = M.n[t];
    const int nrel = M.nrel[t];
    const unsigned short* hbp = hb + (size_t)M.noffH[t];

    const int tid = threadIdx.x;
    const int lane = tid & 63;
    const int wave = tid >> 6;
    const int wr = wave >> 2;
    const int wc = wave & 3;
    const int l15 = lane & 15;
    const int lq  = lane >> 4;
    const int c0 = wc * 32 + l15;

    const int r0 = lb * 128;
    const int rows = min(128, n - r0);
    const bool full = (rows == 128);

    // stage relation rl's z tile into zt (linear copy; data already swizzled)
    auto stage = [&](const unsigned short* z) {
        const unsigned short* zsrc = z + (size_t)r0 * H;
        if (full) {
#pragma unroll
            for (int it = 0; it < 4; ++it) {
                const int off = (wave * 4 + it) * 512;  // ushorts, 1024B chunks
                GLDS16(zsrc + off + lane * 8, zt + off);
            }
        } else {
            for (int idx = tid; idx < rows * 16; idx += 512) {
                *(uint4*)&zt[idx * 8] = *(const uint4*)&zsrc[idx * 8];
            }
        }
    };

    const float bn_inv = 0.99999500003749977f;
    const f32x4 Z4 = {0.f, 0.f, 0.f, 0.f};
    f32x4 acc2[4][2];
#pragma unroll
    for (int rb = 0; rb < 4; ++rb)
#pragma unroll
        for (int nf = 0; nf < 2; ++nf) acc2[rb][nf] = Z4;
    float b2s0 = 0.f, b2s1 = 0.f;

    stage(M.z[t][0]);   // relation 0: latency exposed once

    for (int rl = 0; rl < nrel; ++rl) {
        const int lr = M.lr[t][rl];
        const unsigned short* wp = wprep + (size_t)lr * 32768;
        // preload GEMM1 weight fragments (completes at the barrier)
        short8 w1f[2][4];
#pragma unroll
        for (int nf = 0; nf < 2; ++nf)
#pragma unroll
            for (int kc = 0; kc < 4; ++kc)
                w1f[nf][kc] = *(const short8*)&wp[(c0 + nf * 16) * H + kc * 32 + (lq << 3)];
        const float b1c0 = b1g[lr * H + c0],            b1c1 = b1g[lr * H + c0 + 16];
        const float sc0  = g1g[lr * H + c0] * bn_inv,   sc1  = g1g[lr * H + c0 + 16] * bn_inv;
        const float be0  = be1g[lr * H + c0],           be1v = be1g[lr * H + c0 + 16];
        b2s0 += b2g[lr * H + c0]; b2s1 += b2g[lr * H + c0 + 16];

        __syncthreads();  // A: drains staging (vmcnt(0)) -> zt ready

        // ---- GEMM1: zt @ W1 (pure LDS + regs) ----
        f32x4 acc1[4][2];
#pragma unroll
        for (int rb = 0; rb < 4; ++rb)
#pragma unroll
            for (int nf = 0; nf < 2; ++nf) acc1[rb][nf] = Z4;
#pragma unroll
        for (int kc = 0; kc < 4; ++kc) {
            const int kb = kc * 32 + (lq << 3);
            short8 af[4];
#pragma unroll
            for (int rb = 0; rb < 4; ++rb) {
                const int row = wr * 64 + rb * 16 + l15;
                af[rb] = *(const short8*)&zt[row * H + (kb ^ ((row & 7) << 3))];
            }
#pragma unroll
            for (int rb = 0; rb < 4; ++rb)
#pragma unroll
                for (int nf = 0; nf < 2; ++nf)
                    acc1[rb][nf] = __builtin_amdgcn_mfma_f32_16x16x32_bf16(
                        af[rb], w1f[nf][kc], acc1[rb][nf], 0, 0, 0);
        }
        // epilogue1: BN+ReLU -> a1t (swizzled)
#pragma unroll
        for (int rb = 0; rb < 4; ++rb)
#pragma unroll
            for (int nf = 0; nf < 2; ++nf) {
                const int col = c0 + nf * 16;
                const float b1c = nf == 0 ? b1c0 : b1c1;
                const float scv = nf == 0 ? sc0 : sc1;
                const float bev = nf == 0 ? be0 : be1v;
#pragma unroll
                for (int rg = 0; rg < 4; ++rg) {
                    const int row = wr * 64 + rb * 16 + (lq << 2) + rg;
                    float v = fmaxf((acc1[rb][nf][rg] + b1c) * scv + bev, 0.f);
                    a1t[row * H + (col ^ ((row & 7) << 3))] = f2bf(v);
                }
            }
        __syncthreads();  // B: a1t ready; zt now dead

        if (rl + 1 < nrel) stage(M.z[t][rl + 1]);  // flies under GEMM2

        // ---- GEMM2: a1t @ W2, C chained in acc2 ----
#pragma unroll
        for (int kc = 0; kc < 4; ++kc) {
            const int kb = kc * 32 + (lq << 3);
            short8 af[4], wf[2];
#pragma unroll
            for (int rb = 0; rb < 4; ++rb) {
                const int row = wr * 64 + rb * 16 + l15;
                af[rb] = *(const short8*)&a1t[row * H + (kb ^ ((row & 7) << 3))];
            }
#pragma unroll
            for (int nf = 0; nf < 2; ++nf)
                wf[nf] = *(const short8*)&wp[16384 + (c0 + nf * 16) * H + kb];
#pragma unroll
            for (int rb = 0; rb < 4; ++rb)
#pragma unroll
                for (int nf = 0; nf < 2; ++nf)
                    acc2[rb][nf] = __builtin_amdgcn_mfma_f32_16x16x32_bf16(
                        af[rb], wf[nf], acc2[rb][nf], 0, 0, 0);
        }
    }

    // ---- final epilogue: hnew = elu(acc2 + sum(b2) + hb) ----
    if (fin) {
        float* foutp = fout + (size_t)M.noffH[t];
#pragma unroll
        for (int rb = 0; rb < 4; ++rb)
#pragma unroll
            for (int nf = 0; nf < 2; ++nf) {
                const int col = c0 + nf * 16;
                const float b2s = nf == 0 ? b2s0 : b2s1;
#pragma unroll
                for (int rg = 0; rg < 4; ++rg) {
                    const int row = wr * 64 + rb * 16 + (lq << 2) + rg;
                    if (row < rows) {
                        const size_t o = (size_t)(r0 + row) * H + col;
                        foutp[o] = eluf(acc2[rb][nf][rg] + b2s
                                        + bf2f((unsigned int)hbp[o]));
                    }
                }
            }
    } else {
        unsigned short* hbwp = hbw + (size_t)M.noffH[t];
        __syncthreads();  // all GEMM2 reads of a1t done
#pragma unroll
        for (int rb = 0; rb < 4; ++rb)
#pragma unroll
            for (int nf = 0; nf < 2; ++nf) {
                const int col = c0 + nf * 16;
                const float b2s = nf == 0 ? b2s0 : b2s1;
#pragma unroll
                for (int rg = 0; rg < 4; ++rg) {
                    const int row = wr * 64 + rb * 16 + (lq << 2) + rg;
                    if (row < rows) {
                        const size_t o = (size_t)(r0 + row) * H + col;
                        a1t[row * H + col] = f2bf(eluf(acc2[rb][nf][rg] + b2s
                                                       + bf2f((unsigned int)hbp[o])));
                    }
                }
            }
        __syncthreads();
        uint2* d = (uint2*)&hbwp[(size_t)r0 * H];
        const uint2* s2 = (const uint2*)a1t;
        for (int idx = tid; idx < rows * 32; idx += 512) d[idx] = s2[idx];
    }
}

static inline int imin(int a, int b) { return a < b ? a : b; }
static inline size_t alignup(size_t x) { return (x + 255) & ~(size_t)255; }

extern "C" void kernel_launch(void* const* d_in, const int* in_sizes, int n_in,
                              void* d_out, int out_size, void* d_ws, size_t ws_size,
                              hipStream_t stream) {
    const float* xin[3] = {(const float*)d_in[0], (const float*)d_in[1], (const float*)d_in[2]};
    const int* src[7]; const int* dst[7]; const float* ea[7]; int E[7];
    for (int r = 0; r < 7; ++r) {
        src[r] = (const int*)d_in[3 + 3 * r];
        dst[r] = (const int*)d_in[4 + 3 * r];
        ea[r]  = (const float*)d_in[5 + 3 * r];
        E[r]   = in_sizes[3 + 3 * r];
    }
    const float* linW[3] = {(const float*)d_in[24], (const float*)d_in[26], (const float*)d_in[28]};
    const float* linb[3] = {(const float*)d_in[25], (const float*)d_in[27], (const float*)d_in[29]};
    const float* eW  = (const float*)d_in[30];
    const float* ebp = (const float*)d_in[31];
    const float* W1  = (const float*)d_in[32];
    const float* b1  = (const float*)d_in[33];
    const float* g1  = (const float*)d_in[34];
    const float* be1 = (const float*)d_in[35];
    const float* W2  = (const float*)d_in[36];
    const float* b2  = (const float*)d_in[37];

    const int NSn[3]  = {in_sizes[0] / 64, in_sizes[1] / 64, in_sizes[2] / 64};
    const int NTOT = NSn[0] + NSn[1] + NSn[2];
    const int noff[3] = {0, NSn[0], NSn[0] + NSn[1]};

    float* fout = (float*)d_out;

    // prefixes
    int eOff[8]; eOff[0] = 0;
    for (int r = 0; r < 7; ++r) eOff[r + 1] = eOff[r] + E[r];
    const int Etot = eOff[7];
    int bOff[8]; bOff[0] = 0;
    for (int r = 0; r < 7; ++r) bOff[r + 1] = bOff[r] + (NSn[DST_T_[r]] + 255) / 256;
    int gOff[8]; gOff[0] = 0;
    for (int r = 0; r < 7; ++r) gOff[r + 1] = gOff[r] + (NSn[DST_T_[r]] + 63) / 64;

    // workspace carve-up
    char* wsb = (char*)d_ws;
    size_t off = 0;
    unsigned short* hb = (unsigned short*)(wsb + off); off = alignup(off + (size_t)NTOT * H * 2);
    unsigned short* zb[7];
    for (int r = 0; r < 7; ++r) {
        int nd = NSn[DST_T_[r]];
        zb[r] = (unsigned short*)(wsb + off); off = alignup(off + (size_t)nd * H * 2);
    }
    unsigned short* wprep = (unsigned short*)(wsb + off); off = alignup(off + (size_t)21 * 32768 * 2);
    int* deg    = (int*)(wsb + off); off = alignup(off + (size_t)bOff[7] * 256 * 4);
    int* cursor = (int*)(wsb + off); off = alignup(off + (size_t)bOff[7] * 256 * 4);
    int* bsum   = (int*)(wsb + off); off = alignup(off + (size_t)bOff[7] * 4 + 256);
    int* ptrs[7]; int* csrs[7]; uint2* ceas[7];
    for (int r = 0; r < 7; ++r) {
        int nd = NSn[DST_T_[r]];
        ptrs[r] = (int*)(wsb + off); off = alignup(off + (size_t)(nd + 1) * 4);
    }
    for (int r = 0; r < 7; ++r) {
        csrs[r] = (int*)(wsb + off); off = alignup(off + (size_t)E[r] * 4);
    }
    for (int r = 0; r < 7; ++r) {
        ceas[r] = (uint2*)(wsb + off); off = alignup(off + (size_t)E[r] * 8);
    }

    // ---- batched CSR build ----
    CsrCtx C;
    for (int r = 0; r < 7; ++r) {
        C.src[r] = src[r]; C.dst[r] = dst[r]; C.ea[r] = ea[r];
        C.csr_src[r] = csrs[r]; C.csr_ea[r] = ceas[r]; C.ptr[r] = ptrs[r];
        C.nd[r] = NSn[DST_T_[r]];
    }
    C.deg = deg; C.cursor = cursor; C.bsum = bsum;
    for (int r = 0; r < 8; ++r) { C.eOff[r] = eOff[r]; C.bOff[r] = bOff[r]; }

    hipMemsetAsync(deg, 0, (size_t)bOff[7] * 256 * 4, stream);
    k_hist_all<<<imin((Etot + 255) / 256, 8192), 256, 0, stream>>>(C, Etot);
    k_scan_partial_all<<<bOff[7], 256, 0, stream>>>(C);
    k_scan_mid_all<<<7, 512, 0, stream>>>(C);
    k_scan_final_all<<<bOff[7], 256, 0, stream>>>(C);
    k_scatter_all<<<imin((Etot + 255) / 256, 8192), 256, 0, stream>>>(C, Etot);
    k_wprep<<<1344, 256, 0, stream>>>(W1, W2, wprep, 21 * 16384);

    // ---- input embeddings (bf16 h) ----
    for (int t = 0; t < 3; ++t) {
        int n = NSn[t];
        k_input_linear<<<imin((n + 15) / 16, 2048), 128, 0, stream>>>(
            xin[t], linW[t], linb[t], hb + (size_t)noff[t] * H, n);
    }

    // ---- agg context ----
    AggCtx A;
    for (int r = 0; r < 7; ++r) {
        A.ptr[r] = ptrs[r]; A.csr_src[r] = csrs[r]; A.csr_ea[r] = ceas[r];
        A.hsrc[r] = hb + (size_t)noff[SRC_T_[r]] * H;
        A.hdst[r] = hb + (size_t)noff[DST_T_[r]] * H;
        A.z[r] = zb[r];
        A.nd[r] = NSn[DST_T_[r]];
    }
    for (int r = 0; r < 8; ++r) A.gOff[r] = gOff[r];

    // ---- mlp context ----
    static const int RELS[3][3] = {{0, 2, 0}, {1, 3, 5}, {4, 6, 0}};
    static const int NRELS[3] = {2, 3, 2};
    MlpCtx M;
    int gend = 0;
    for (int t = 0; t < 3; ++t) {
        M.nrel[t] = NRELS[t];
        M.noffH[t] = noff[t] * H;
        M.n[t] = NSn[t];
        gend += (NSn[t] + 127) / 128;
        M.gend[t] = gend;
        for (int k = 0; k < 3; ++k) M.z[t][k] = zb[RELS[t][k]];
    }

    // ---- layers ----
    for (int l = 0; l < 3; ++l) {
        const int fin = (l == 2) ? 1 : 0;
        k_aggz_all<<<gOff[7], 256, 0, stream>>>(A, eW, ebp, l);
        for (int t = 0; t < 3; ++t)
            for (int k = 0; k < 3; ++k) M.lr[t][k] = l * 7 + RELS[t][k];
        k_mlp_all<<<M.gend[2], 512, 0, stream>>>(
            M, hb, hb, fout, wprep, b1, g1, be1, b2, fin);
    }
}